// Round 7
// baseline (962.011 us; speedup 1.0000x reference)
//
#include <hip/hip_runtime.h>
#include <stdint.h>
#include <math.h>

#define DEVI __device__ __forceinline__

// Problem constants (B,T,H,E fixed by the reference setup)
constexpr int TB  = 2;
constexpr int TT  = 4096;
constexpr int TH  = 8;
constexpr int TE  = 64;
constexpr int TBH = 16;   // B*H
constexpr int TM  = 256;  // performer features
constexpr int TNH = 4;    // hash rounds
constexpr float C_TEMP  = 0.125f;                 // 1/sqrt(E)
constexpr float C_DN    = 0.35355339059327373f;   // sqrt(temp)
constexpr float C_RATIO = 0.0625f;                // M^-0.5

typedef __attribute__((ext_vector_type(8))) short bf16x8;
typedef __attribute__((ext_vector_type(4))) float f32x4;

// ---------------- workspace layout ----------------
constexpr size_t algn(size_t x){ return (x + 255) & ~(size_t)255; }
constexpr size_t OFF_QN2F = 0;
constexpr size_t OFF_KN2F = algn(OFF_QN2F + (size_t)TBH*TT*4);
constexpr size_t OFF_QN2D = algn(OFF_KN2F + (size_t)TBH*TT*4);
constexpr size_t OFF_KN2D = algn(OFF_QN2D + (size_t)TBH*TT*8);
constexpr size_t OFF_MQK2 = algn(OFF_KN2D + (size_t)TBH*TT*8);
constexpr size_t OFF_QMAXP= algn(OFF_MQK2 + (size_t)TBH*8);
constexpr size_t OFF_KMAXP= algn(OFF_QMAXP+ (size_t)TBH*16*8);
constexpr size_t OFF_QH   = algn(OFF_KMAXP+ (size_t)TBH*16*8);
constexpr size_t OFF_KH   = algn(OFF_QH   + (size_t)TNH*TBH*TT*8);
constexpr size_t OFF_QPOS = algn(OFF_KH   + (size_t)TNH*TBH*TT*8);
constexpr size_t OFF_KPOS = algn(OFF_QPOS + (size_t)TNH*TBH*TT*4);
constexpr size_t OFF_QREV = algn(OFF_KPOS + (size_t)TNH*TBH*TT*4);
constexpr size_t OFF_KREV = algn(OFF_QREV + (size_t)TNH*TBH*TT*4);
constexpr size_t OFF_KLSP = algn(OFF_KREV + (size_t)TNH*TBH*TT*4);
constexpr size_t OFF_KLS  = algn(OFF_KLSP + (size_t)TBH*128*4);
constexpr size_t OFF_QP   = algn(OFF_KLS  + (size_t)TBH*4);
constexpr size_t OFF_KP   = algn(OFF_QP   + (size_t)TBH*TT*TM*4);   // dashQ fp32 -> packed hi/lo bf16
constexpr size_t OFF_PLS  = algn(OFF_KP   + (size_t)TBH*TT*TM*4);   // dashK fp32 -> packed hi/lo bf16
constexpr size_t OFF_KSUM = algn(OFF_PLS  + (size_t)TBH*TT*4);
constexpr size_t OFF_KV   = algn(OFF_KSUM + (size_t)TBH*TM*4);
constexpr size_t OFF_OT   = algn(OFF_KV   + (size_t)TBH*TM*TE*4);
constexpr size_t OFF_LSET = algn(OFF_OT   + (size_t)TNH*TBH*TT*TE*4);
constexpr size_t OFF_DSUM = algn(OFF_LSET + (size_t)TNH*TBH*TT*4);
constexpr size_t WS_NEED  = algn(OFF_DSUM + (size_t)TNH*TBH*TT*4);  // ~203 MB
// overlays (dead after k_sort/k_hash): kv partials in qn2d..kh window
constexpr size_t OFF_KVP  = OFF_QN2D;                  // 4 MB (4 x 16 x 256 x 64 f32)
constexpr size_t OFF_KSP  = OFF_KVP + (size_t)4*16*256*64*4;  // 64 KB

// ---------------- helpers ----------------
DEVI float bf2f(uint32_t u16){ uint32_t x = u16 << 16; return __builtin_bit_cast(float, x); }
DEVI uint16_t f2bf(float f){
  uint32_t x = __builtin_bit_cast(uint32_t, f);
  uint32_t r = x + 0x7fffu + ((x >> 16) & 1u);   // RNE
  return (uint16_t)(r >> 16);
}
DEVI int dupc(uint32_t x){
  return (int)((x & 0xffu) == 0) + (int)(((x >> 8) & 0xffu) == 0)
       + (int)(((x >> 16) & 0xffu) == 0) + (int)((x >> 24) == 0);
}
DEVI float lndup(int d){
  return d == 1 ? 0.f : d == 2 ? 0.69314718f : d == 3 ? 1.09861229f : 1.38629436f;
}
DEVI float rcpdup(int d){
  return d == 1 ? 1.f : d == 2 ? 0.5f : d == 3 ? 0.333333343f : 0.25f;
}

// stage 32 floats (half of a 64-wide row) as bf16 hi|lo into a 272B LDS row:
// layout per row: 64 hi shorts | 64 lo shorts | 8 pad shorts
DEVI void stage64(char* rowp, const float4* src8, int hf){
  #pragma unroll
  for(int x = 0; x < 8; x++){
    float4 vv = src8[x];
    uint16_t hx = f2bf(vv.x), hy = f2bf(vv.y), hz = f2bf(vv.z), hw = f2bf(vv.w);
    float lx = vv.x - bf2f(hx), ly = vv.y - bf2f(hy), lz = vv.z - bf2f(hz), lw = vv.w - bf2f(hw);
    uint2 hp = make_uint2((uint32_t)hx | ((uint32_t)hy << 16), (uint32_t)hz | ((uint32_t)hw << 16));
    uint2 lp = make_uint2((uint32_t)f2bf(lx) | ((uint32_t)f2bf(ly) << 16),
                          (uint32_t)f2bf(lz) | ((uint32_t)f2bf(lw) << 16));
    *((uint2*)(rowp + 64*hf + 8*x)) = hp;
    *((uint2*)(rowp + 128 + 64*hf + 8*x)) = lp;
  }
}

// ---------------- K1: row sumsq (f32+f64) + partial max (XBOX+ ext) ----------------
__global__ void k_norms2(const float* __restrict__ q, const float* __restrict__ kk,
                         float* __restrict__ qn2f, float* __restrict__ kn2f,
                         double* __restrict__ qn2d, double* __restrict__ kn2d,
                         double* __restrict__ qmaxp, double* __restrict__ kmaxp){
  __shared__ double red[256];
  int bx = blockIdx.x; int chunk = bx & 15, bh = bx >> 4;
  int tid = threadIdx.x;
  int b = bh >> 3, hh = bh & 7;
  int t = chunk*256 + tid;
  const float4* r1 = (const float4*)(q + (((size_t)(b*TT + t)*TH) + hh)*TE);
  double s = 0.0;
  #pragma unroll
  for(int x = 0; x < 16; x++){
    float4 vv = r1[x];
    s += (double)vv.x*vv.x + (double)vv.y*vv.y + (double)vv.z*vv.z + (double)vv.w*vv.w;
  }
  qn2d[bh*TT + t] = s; qn2f[bh*TT + t] = (float)s;
  const float4* r2 = (const float4*)(kk + (((size_t)(b*TT + t)*TH) + hh)*TE);
  double s2 = 0.0;
  #pragma unroll
  for(int x = 0; x < 16; x++){
    float4 vv = r2[x];
    s2 += (double)vv.x*vv.x + (double)vv.y*vv.y + (double)vv.z*vv.z + (double)vv.w*vv.w;
  }
  kn2d[bh*TT + t] = s2; kn2f[bh*TT + t] = (float)s2;
  red[tid] = s; __syncthreads();
  for(int o = 128; o > 0; o >>= 1){ if(tid < o) red[tid] = fmax(red[tid], red[tid+o]); __syncthreads(); }
  if(tid == 0) qmaxp[bh*16 + chunk] = red[0];
  __syncthreads();
  red[tid] = s2; __syncthreads();
  for(int o = 128; o > 0; o >>= 1){ if(tid < o) red[tid] = fmax(red[tid], red[tid+o]); __syncthreads(); }
  if(tid == 0) kmaxp[bh*16 + chunk] = red[0];
}

__global__ void k_mqk(const double* __restrict__ qmaxp, const double* __restrict__ kmaxp,
                      double* __restrict__ mqk2){
  int bh = blockIdx.x;
  if(threadIdx.x == 0){
    double mq = -1e300, mk = -1e300;
    for(int i = 0; i < 16; i++){ mq = fmax(mq, qmaxp[bh*16 + i]); mk = fmax(mk, kmaxp[bh*16 + i]); }
    mqk2[bh] = mq + mk;
  }
}

// ---------------- K2: E2LSH hashes (float64) ----------------
__global__ void k_hash(const float* __restrict__ q, const float* __restrict__ kk,
                       const float* __restrict__ alpha, const float* __restrict__ beta,
                       const double* __restrict__ qn2d, const double* __restrict__ kn2d,
                       const double* __restrict__ mqk2,
                       double* __restrict__ qh, double* __restrict__ kh){
  __shared__ double al[264];
  __shared__ double be[4];
  int tid = threadIdx.x;
  for(int i = tid; i < 264; i += 256) al[i] = (double)alpha[i];
  if(tid < 4) be[tid] = (double)beta[tid];
  __syncthreads();
  int gid = blockIdx.x*256 + tid;
  int side = gid >> 16; int r = gid & 65535;
  int bh = r >> 12, t = r & 4095;
  int b = bh >> 3, hh = bh & 7;
  const float* x = (side ? kk : q) + (((size_t)(b*TT + t)*TH) + hh)*TE;
  const float4* xr = (const float4*)x;
  double a0 = 0.0, a1 = 0.0, a2 = 0.0, a3 = 0.0;
  #pragma unroll
  for(int c = 0; c < 16; c++){
    float4 vv = xr[c];
    const double* a = al + c*16;
    a0 += (double)vv.x*a[0]  + (double)vv.y*a[4]  + (double)vv.z*a[8]  + (double)vv.w*a[12];
    a1 += (double)vv.x*a[1]  + (double)vv.y*a[5]  + (double)vv.z*a[9]  + (double)vv.w*a[13];
    a2 += (double)vv.x*a[2]  + (double)vv.y*a[6]  + (double)vv.z*a[10] + (double)vv.w*a[14];
    a3 += (double)vv.x*a[3]  + (double)vv.y*a[7]  + (double)vv.z*a[11] + (double)vv.w*a[15];
  }
  double n2  = (side ? kn2d : qn2d)[bh*TT + t];
  double ext = sqrt(fmax(mqk2[bh] - n2, 0.0));
  int ec = side ? 65 : 64;
  double* dst = side ? kh : qh;
  dst[((size_t)0*TBH + bh)*TT + t] = a0 + ext*al[ec*4 + 0] + be[0];
  dst[((size_t)1*TBH + bh)*TT + t] = a1 + ext*al[ec*4 + 1] + be[1];
  dst[((size_t)2*TBH + bh)*TT + t] = a2 + ext*al[ec*4 + 2] + be[2];
  dst[((size_t)3*TBH + bh)*TT + t] = a3 + ext*al[ec*4 + 3] + be[3];
}

// ---------------- K3: stable argsort via bitonic on doubles (1024 thr) ----------------
__global__ void k_sort(const double* __restrict__ qh, const double* __restrict__ kh,
                       int* __restrict__ qpos, int* __restrict__ kpos,
                       int* __restrict__ qrev, int* __restrict__ krev){
  __shared__ double v[4096];
  __shared__ int    ix[4096];
  int blk = blockIdx.x; int side = blk >> 6; int hb = blk & 63;
  const double* src = (side ? kh : qh) + (size_t)hb*TT;
  int tid = threadIdx.x;
  for(int i = tid; i < 4096; i += 1024){ v[i] = src[i]; ix[i] = i; }
  __syncthreads();
  for(int k = 2; k <= 4096; k <<= 1){
    for(int j = k >> 1; j > 0; j >>= 1){
      for(int i = tid; i < 4096; i += 1024){
        int l = i ^ j;
        if(l > i){
          double va = v[i], vb = v[l]; int ia = ix[i], ib = ix[l];
          bool gt  = (va > vb) || (va == vb && ia > ib);
          bool asc = ((i & k) == 0);
          if(gt == asc){ v[i] = vb; v[l] = va; ix[i] = ib; ix[l] = ia; }
        }
      }
      __syncthreads();
    }
  }
  int* pos = (side ? kpos : qpos) + (size_t)hb*TT;
  int* rev = (side ? krev : qrev) + (size_t)hb*TT;
  for(int i = tid; i < 4096; i += 1024){ int id = ix[i]; pos[i] = id; rev[id] = i; }
}

// ---------------- K4: dash GEMM (both sides) -> dash[bh][t][m] fp32 ----------------
__launch_bounds__(512, 1)
__global__ void k_dash(const float* __restrict__ q, const float* __restrict__ kk,
                       const float* __restrict__ proj,
                       const float* __restrict__ qn2f, const float* __restrict__ kn2f,
                       float* __restrict__ qdash, float* __restrict__ kdash){
  __shared__ __align__(16) float pjL[64*260];    // 66.6 KB
  __shared__ __align__(16) float x_l[128*68];    // 34.8 KB
  __shared__ float x_n[128];
  int tid = threadIdx.x;
  int bx = blockIdx.x;
  int side = bx >> 9; int r = bx & 511; int bh = r >> 5; int ch = r & 31;
  int b = bh >> 3, hh = bh & 7, t0 = ch*128;
  const float* x  = side ? kk   : q;
  const float* n2 = side ? kn2f : qn2f;
  float* outp     = side ? kdash : qdash;

  #pragma unroll 8
  for(int it = 0; it < 32; it++){
    int idx = it*512 + tid;
    pjL[(idx & 63)*260 + (idx >> 6)] = proj[idx];
  }
  {
    int rr = tid >> 2, c = tid & 3;
    const float4* src = (const float4*)(x + (((size_t)(b*TT + t0 + rr)*TH) + hh)*TE);
    float4* dst = (float4*)(x_l + rr*68);
    #pragma unroll
    for(int i = 0; i < 4; i++) dst[c*4 + i] = src[c*4 + i];
  }
  if(tid < 128) x_n[tid] = n2[bh*TT + t0 + tid];
  __syncthreads();

  int ml = (tid & 15)*4;
  int tb = tid >> 4;   // 0..31
  float4 acc[4][4];
  #pragma unroll
  for(int tt = 0; tt < 4; tt++)
    #pragma unroll
    for(int g = 0; g < 4; g++) acc[tt][g] = make_float4(0.f,0.f,0.f,0.f);

  #pragma unroll 4
  for(int k4 = 0; k4 < 16; k4++){
    float4 xv[4];
    #pragma unroll
    for(int tt = 0; tt < 4; tt++)
      xv[tt] = *((const float4*)(x_l + (tb + 32*tt)*68 + k4*4));
    #pragma unroll
    for(int kk4 = 0; kk4 < 4; kk4++){
      int krow = k4*4 + kk4;
      #pragma unroll
      for(int g = 0; g < 4; g++){
        float4 pv = *((const float4*)(pjL + krow*260 + ml + 64*g));
        #pragma unroll
        for(int tt = 0; tt < 4; tt++){
          float xs = (kk4 == 0) ? xv[tt].x : (kk4 == 1) ? xv[tt].y : (kk4 == 2) ? xv[tt].z : xv[tt].w;
          acc[tt][g].x = fmaf(xs, pv.x, acc[tt][g].x);
          acc[tt][g].y = fmaf(xs, pv.y, acc[tt][g].y);
          acc[tt][g].z = fmaf(xs, pv.z, acc[tt][g].z);
          acc[tt][g].w = fmaf(xs, pv.w, acc[tt][g].w);
        }
      }
    }
  }
  #pragma unroll
  for(int tt = 0; tt < 4; tt++){
    int t_r = tb + 32*tt;
    float diag = 0.5f*C_TEMP*x_n[t_r];
    size_t rowbase = ((size_t)bh*TT + t0 + t_r)*256;
    #pragma unroll
    for(int g = 0; g < 4; g++){
      float4 a = acc[tt][g];
      float4 dd;
      dd.x = fmaf(C_DN, a.x, -diag); dd.y = fmaf(C_DN, a.y, -diag);
      dd.z = fmaf(C_DN, a.z, -diag); dd.w = fmaf(C_DN, a.w, -diag);
      *((float4*)(outp + rowbase + ml + 64*g)) = dd;
    }
  }
}

// ---------------- K4b: max over dashK chunks -> klsp ----------------
__global__ void k_klsmax(const float* __restrict__ kdash, float* __restrict__ klsp){
  __shared__ float wr[4];
  int tid = threadIdx.x;
  int bx = blockIdx.x; int bh = bx >> 7, ch = bx & 127;
  const float4* src = (const float4*)(kdash + ((size_t)bh << 20)) + ch*2048;
  float mx = -1e30f;
  #pragma unroll
  for(int i = 0; i < 8; i++){
    float4 vv = src[i*256 + tid];
    mx = fmaxf(mx, fmaxf(fmaxf(vv.x, vv.y), fmaxf(vv.z, vv.w)));
  }
  #pragma unroll
  for(int o = 32; o > 0; o >>= 1) mx = fmaxf(mx, __shfl_xor(mx, o, 64));
  if((tid & 63) == 0) wr[tid >> 6] = mx;
  __syncthreads();
  if(tid == 0) klsp[bh*128 + ch] = fmaxf(fmaxf(wr[0], wr[1]), fmaxf(wr[2], wr[3]));
}

__global__ void k_klsred(const float* __restrict__ klsp, float* __restrict__ kls){
  __shared__ float red[2];
  int bh = blockIdx.x, tid = threadIdx.x;
  float v = klsp[bh*128 + tid];
  #pragma unroll
  for(int o = 32; o > 0; o >>= 1) v = fmaxf(v, __shfl_xor(v, o, 64));
  if((tid & 63) == 0) red[tid >> 6] = v;
  __syncthreads();
  if(tid == 0) kls[bh] = fmaxf(red[0], red[1]);
}

// ---------------- K4c: kp = exp(dashK - kls)*ratio, packed hi/lo, in place ----------------
// Row (1KB) becomes 4 chunks of [64 hi shorts | 64 lo shorts]. One wave owns one
// row: all loads precede all stores in one instruction stream -> race-free.
__global__ void k_expk(float* __restrict__ kp, const float* __restrict__ kls){
  int tid = threadIdx.x, wid = tid >> 6, lane = tid & 63;
  int row = blockIdx.x*4 + wid;
  float stab = kls[row >> 12];
  float* rp = kp + (size_t)row*256;
  float4 vv = ((const float4*)rp)[lane];
  float e0 = __expf(vv.x - stab)*C_RATIO, e1 = __expf(vv.y - stab)*C_RATIO;
  float e2 = __expf(vv.z - stab)*C_RATIO, e3 = __expf(vv.w - stab)*C_RATIO;
  uint16_t h0 = f2bf(e0), h1 = f2bf(e1), h2 = f2bf(e2), h3 = f2bf(e3);
  uint2 hp = make_uint2((uint32_t)h0 | ((uint32_t)h1 << 16), (uint32_t)h2 | ((uint32_t)h3 << 16));
  uint2 lp = make_uint2((uint32_t)f2bf(e0 - bf2f(h0)) | ((uint32_t)f2bf(e1 - bf2f(h1)) << 16),
                        (uint32_t)f2bf(e2 - bf2f(h2)) | ((uint32_t)f2bf(e3 - bf2f(h3)) << 16));
  char* rb = (char*)rp;
  int c = lane >> 4, i = (lane & 15)*4;
  *((uint2*)(rb + c*256 + 2*i)) = hp;
  *((uint2*)(rb + c*256 + 128 + 2*i)) = lp;
}

// ---------------- K4d: qp = exp(dashQ - rowmax)*ratio packed hi/lo, pls = rowmax ----------------
__global__ void k_expq(float* __restrict__ qp, float* __restrict__ pls){
  int tid = threadIdx.x, wid = tid >> 6, lane = tid & 63;
  int row = blockIdx.x*4 + wid;
  float* rp = qp + (size_t)row*256;
  float4 vv = ((const float4*)rp)[lane];
  float mr = fmaxf(fmaxf(vv.x, vv.y), fmaxf(vv.z, vv.w));
  #pragma unroll
  for(int o = 32; o > 0; o >>= 1) mr = fmaxf(mr, __shfl_xor(mr, o, 64));
  float e0 = __expf(vv.x - mr)*C_RATIO, e1 = __expf(vv.y - mr)*C_RATIO;
  float e2 = __expf(vv.z - mr)*C_RATIO, e3 = __expf(vv.w - mr)*C_RATIO;
  uint16_t h0 = f2bf(e0), h1 = f2bf(e1), h2 = f2bf(e2), h3 = f2bf(e3);
  uint2 hp = make_uint2((uint32_t)h0 | ((uint32_t)h1 << 16), (uint32_t)h2 | ((uint32_t)h3 << 16));
  uint2 lp = make_uint2((uint32_t)f2bf(e0 - bf2f(h0)) | ((uint32_t)f2bf(e1 - bf2f(h1)) << 16),
                        (uint32_t)f2bf(e2 - bf2f(h2)) | ((uint32_t)f2bf(e3 - bf2f(h3)) << 16));
  char* rb = (char*)rp;
  int c = lane >> 4, i = (lane & 15)*4;
  *((uint2*)(rb + c*256 + 2*i)) = hp;
  *((uint2*)(rb + c*256 + 128 + 2*i)) = lp;
  if(lane == 0) pls[row] = mr;
}

// ---------------- K5: kv partials over s-chunks (packed kp), then reduce ----------------
__global__ void k_kv2(const float* __restrict__ kp, const float* __restrict__ v,
                      float* __restrict__ kvp, float* __restrict__ ksump){
  int bx = blockIdx.x; int sc = bx >> 7; int rem = bx & 127; int bh = rem >> 3; int mt = rem & 7;
  int tid = threadIdx.x; int g = tid >> 6, d = tid & 63;
  int b = bh >> 3, hh = bh & 7; int m0 = mt*32;
  int mbase = m0 + 8*g;              // 8 consecutive m, within one 64-chunk
  int c = mbase >> 6, i0 = mbase & 63;
  float a[8], sa[8];
  #pragma unroll
  for(int j = 0; j < 8; j++){ a[j] = 0.f; sa[j] = 0.f; }
  const char* kpB = (const char*)kp + (size_t)bh*TT*1024 + c*256 + 2*i0;
  const float* vb = v + (size_t)b*TT*TH*TE + hh*TE + d;
  int s0 = sc*1024;
  #pragma unroll 2
  for(int s = s0; s < s0 + 1024; s++){
    float vv = vb[(size_t)s*512];
    const char* rp = kpB + (size_t)s*1024;
    uint4 h4 = *((const uint4*)rp);
    uint4 l4 = *((const uint4*)(rp + 128));
    float f[8];
    f[0] = bf2f(h4.x & 0xffffu) + bf2f(l4.x & 0xffffu);
    f[1] = bf2f(h4.x >> 16)     + bf2f(l4.x >> 16);
    f[2] = bf2f(h4.y & 0xffffu) + bf2f(l4.y & 0xffffu);
    f[3] = bf2f(h4.y >> 16)     + bf2f(l4.y >> 16);
    f[4] = bf2f(h4.z & 0xffffu) + bf2f(l4.z & 0xffffu);
    f[5] = bf2f(h4.z >> 16)     + bf2f(l4.z >> 16);
    f[6] = bf2f(h4.w & 0xffffu) + bf2f(l4.w & 0xffffu);
    f[7] = bf2f(h4.w >> 16)     + bf2f(l4.w >> 16);
    #pragma unroll
    for(int j = 0; j < 8; j++){ a[j] = fmaf(f[j], vv, a[j]); sa[j] += f[j]; }
  }
  #pragma unroll
  for(int j = 0; j < 8; j++){
    int m = mbase + j;
    kvp[(((size_t)sc*16 + bh)*256 + m)*64 + d] = a[j];
    if(d == 0) ksump[((size_t)sc*16 + bh)*256 + m] = sa[j];
  }
}

__global__ void k_kvred(const float* __restrict__ kvp, const float* __restrict__ ksump,
                        float* __restrict__ kv, float* __restrict__ ksum){
  int bx = blockIdx.x, tid = threadIdx.x;
  if(bx < 256){
    size_t i = (size_t)bx*1024 + tid*4;
    float4 s = make_float4(0.f,0.f,0.f,0.f);
    #pragma unroll
    for(int sc = 0; sc < 4; sc++){
      float4 p = *((const float4*)(kvp + (size_t)sc*262144 + i));
      s.x += p.x; s.y += p.y; s.z += p.z; s.w += p.w;
    }
    *((float4*)(kv + i)) = s;
  } else {
    for(int m = tid; m < 4096; m += 256){
      float s = 0.f;
      #pragma unroll
      for(int sc = 0; sc < 4; sc++) s += ksump[sc*4096 + m];
      ksum[m] = s;
    }
  }
}

// ---------------- K6: per-bucket attention, MFMA split-bf16 ----------------
__launch_bounds__(256, 2)
__global__ void k_bucket(const float* __restrict__ q, const float* __restrict__ kk, const float* __restrict__ v,
                         const float* __restrict__ qp, const float* __restrict__ kp,
                         const int* __restrict__ qpos, const int* __restrict__ kpos,
                         const int* __restrict__ qrev, const int* __restrict__ krev,
                         const float* __restrict__ pls, const float* __restrict__ kls,
                         const float* __restrict__ qn2f, const float* __restrict__ kn2f,
                         float* __restrict__ o_t, float* __restrict__ lse_t, float* __restrict__ dsum_t){
  __shared__ __align__(16) char smem[73232];
  constexpr int OFS_B = 34816;
  int* qidxL   = (int*)(smem + 69632);
  int* kidxL   = (int*)(smem + 70144);
  int* qbpL    = (int*)(smem + 70656);
  int* kbpL    = (int*)(smem + 71168);
  float* lseL  = (float*)(smem + 71680);
  float* pfacL = (float*)(smem + 72192);
  float* kn2L  = (float*)(smem + 72704);
  float* kmaxP = (float*)(smem + 73216);

  int tid = threadIdx.x;
  int w = tid >> 6, lane = tid & 63, l15 = lane & 15, quad = lane >> 4;
  int bx = blockIdx.x; int n = bx & 31, bh = (bx >> 5) & 15, h = bx >> 9;
  int b = bh >> 3, hh = bh & 7;

  if(tid < 128){
    int tk = kpos[((size_t)h*TBH + bh)*TT + n*128 + tid];
    kidxL[tid] = tk;
    int pk = 0;
    #pragma unroll
    for(int h3 = 0; h3 < 4; h3++){ int rv = krev[((size_t)h3*TBH + bh)*TT + tk]; pk |= (rv >> 7) << (8*h3); }
    kbpL[tid] = pk;
    kn2L[tid] = kn2f[(size_t)bh*TT + tk];
    int tq = qpos[((size_t)h*TBH + bh)*TT + n*128 + tid];
    qidxL[tid] = tq;
    int pq = 0;
    #pragma unroll
    for(int h3 = 0; h3 < 4; h3++){ int rv = qrev[((size_t)h3*TBH + bh)*TT + tq]; pq |= (rv >> 7) << (8*h3); }
    qbpL[tid] = pq;
  }
  __syncthreads();
  if(tid < 64){
    float m = fmaxf(kn2L[tid], kn2L[tid + 64]);
    #pragma unroll
    for(int o = 32; o > 0; o >>= 1) m = fmaxf(m, __shfl_xor(m, o, 64));
    if(tid == 0) kmaxP[0] = m;
  }
  {  // stage Q into bufA, K into bufB (fp32 -> bf16 hi/lo)
    int r = tid >> 1, hf = tid & 1;
    const float4* qs = (const float4*)(q  + (((size_t)(b*TT + qidxL[r])*TH) + hh)*TE) + hf*8;
    const float4* ks = (const float4*)(kk + (((size_t)(b*TT + kidxL[r])*TH) + hh)*TE) + hf*8;
    stage64(smem + r*272, qs, hf);
    stage64(smem + OFS_B + r*272, ks, hf);
  }
  __syncthreads();
  if(tid < 128){  // per-row stabilizer (Cauchy-Schwarz UB) + pfac
    int tq = qidxL[tid];
    float plsv = pls[(size_t)bh*TT + tq] + kls[bh];
    float lse = fmaxf(plsv, C_TEMP * sqrtf(qn2f[(size_t)bh*TT + tq] * kmaxP[0]));
    lseL[tid] = lse;
    pfacL[tid] = __expf(plsv - lse);
  }

  f32x4 acc_s[2][8], acc_p[2][8];
  #pragma unroll
  for(int mt = 0; mt < 2; mt++)
    #pragma unroll
    for(int nt = 0; nt < 8; nt++){
      acc_s[mt][nt] = (f32x4){0.f,0.f,0.f,0.f};
      acc_p[mt][nt] = (f32x4){0.f,0.f,0.f,0.f};
    }

  {  // S = Q K^T (K=64, split-3)
    bf16x8 ahi[2][2], alo[2][2];
    #pragma unroll
    for(int mt = 0; mt < 2; mt++)
      #pragma unroll
      for(int ks = 0; ks < 2; ks++){
        const char* ap = smem + (32*w + 16*mt + l15)*272 + 64*ks + 16*quad;
        ahi[mt][ks] = *((const bf16x8*)ap);
        alo[mt][ks] = *((const bf16x8*)(ap + 128));
      }
    #pragma unroll
    for(int nt = 0; nt < 8; nt++){
      #pragma unroll
      for(int ks = 0; ks < 2; ks++){
        const char* bp = smem + OFS_B + (16*nt + l15)*272 + 64*ks + 16*quad;
        bf16x8 bhi = *((const bf16x8*)bp);
        bf16x8 blo = *((const bf16x8*)(bp + 128));
        #pragma unroll
        for(int mt = 0; mt < 2; mt++){
          acc_s[mt][nt] = __builtin_amdgcn_mfma_f32_16x16x32_bf16(ahi[mt][ks], bhi, acc_s[mt][nt], 0, 0, 0);
          acc_s[mt][nt] = __builtin_amdgcn_mfma_f32_16x16x32_bf16(ahi[mt][ks], blo, acc_s[mt][nt], 0, 0, 0);
          acc_s[mt][nt] = __builtin_amdgcn_mfma_f32_16x16x32_bf16(alo[mt][ks], bhi, acc_s[mt][nt], 0, 0, 0);
        }
      }
    }
  }
  __syncthreads();

  // DP = QP KP^T (K=256 in 4 chunks of 64, split-3). qp/kp already packed
  // [64 hi | 64 lo] per chunk -> staging is a raw 128B copy per half-thread.
  for(int c = 0; c < 4; c++){
    { int r = tid >> 1, hf = tid & 1;
      const uint4* qs = (const uint4*)((const char*)qp + ((size_t)bh*TT + qidxL[r])*1024 + c*256 + hf*128);
      const uint4* ks = (const uint4*)((const char*)kp + ((size_t)bh*TT + kidxL[r])*1024 + c*256 + hf*128);
      uint4* dq = (uint4*)(smem + r*272 + hf*128);
      uint4* dk = (uint4*)(smem + OFS_B + r*272 + hf*128);
      #pragma unroll
      for(int i = 0; i < 8; i++){ dq[i] = qs[i]; dk[i] = ks[i]; }
    }
    __syncthreads();
    bf16x8 ahi[2][2], alo[2][2];
    #pragma unroll
    for(int mt = 0; mt < 2; mt++)
      #pragma unroll
      for(int ks = 0; ks < 2; ks++){
        const char* ap = smem + (32*w + 16*mt + l15)*272 + 64*ks + 16*quad;
        ahi[mt][ks] = *((const bf16x8*)ap);
        alo[mt][ks] = *((const bf16x8*)(ap + 128));
      }
    #pragma unroll
    for(int nt = 0; nt < 8; nt++){
      #pragma unroll
      for(int ks = 0; ks < 2; ks++){
        const char* bp = smem + OFS_B + (16*nt + l15)*272 + 64*ks + 16*quad;
        bf16x8 bhi = *((const bf16x8*)bp);
        bf16x8 blo = *((const bf16x8*)(bp + 128));
        #pragma unroll
        for(int mt = 0; mt < 2; mt++){
          acc_p[mt][nt] = __builtin_amdgcn_mfma_f32_16x16x32_bf16(ahi[mt][ks], bhi, acc_p[mt][nt], 0, 0, 0);
          acc_p[mt][nt] = __builtin_amdgcn_mfma_f32_16x16x32_bf16(ahi[mt][ks], blo, acc_p[mt][nt], 0, 0, 0);
          acc_p[mt][nt] = __builtin_amdgcn_mfma_f32_16x16x32_bf16(alo[mt][ks], bhi, acc_p[mt][nt], 0, 0, 0);
        }
      }
    }
    __syncthreads();
  }

  {  // stage V^T into bufB (bf16 hi/lo, transposed)
    int j = tid >> 1, hc = tid & 1;
    const float4* vs = (const float4*)(v + (((size_t)(b*TT + kidxL[j])*TH) + hh)*TE) + hc*8;
    #pragma unroll
    for(int x = 0; x < 8; x++){
      float4 vv = vs[x];
      int c0 = hc*32 + 4*x;
      float vals[4] = {vv.x, vv.y, vv.z, vv.w};
      #pragma unroll
      for(int i = 0; i < 4; i++){
        uint16_t hi = f2bf(vals[i]);
        float lo = vals[i] - bf2f(hi);
        *((uint16_t*)(smem + OFS_B + (c0 + i)*528 + 2*j)) = hi;
        *((uint16_t*)(smem + OFS_B + (c0 + i)*528 + 256 + 2*j)) = f2bf(lo);
      }
    }
  }
  int qbp_r[8]; float lse_r[8], pfac_r[8], dsump[8]; int kbp_c[8];
  #pragma unroll
  for(int i = 0; i < 8; i++){
    int r = 32*w + 16*(i >> 2) + 4*quad + (i & 3);
    qbp_r[i] = qbpL[r]; lse_r[i] = lseL[r]; pfac_r[i] = pfacL[r]; dsump[i] = 0.f;
  }
  #pragma unroll
  for(int nt = 0; nt < 8; nt++) kbp_c[nt] = kbpL[l15 + 16*nt];
  __syncthreads();

  // D (elementwise in C-layout regs) -> LDS bf16 hi/lo -> O += D V (two col-halves)
  f32x4 acc_o[2][4];
  #pragma unroll
  for(int mt = 0; mt < 2; mt++)
    #pragma unroll
    for(int nv = 0; nv < 4; nv++) acc_o[mt][nv] = (f32x4){0.f,0.f,0.f,0.f};

  #pragma unroll
  for(int hv = 0; hv < 2; hv++){
    #pragma unroll
    for(int nt = 0; nt < 4; nt++){
      int ntg = 4*hv + nt;
      #pragma unroll
      for(int mt = 0; mt < 2; mt++){
        f32x4 s4 = acc_s[mt][ntg], p4 = acc_p[mt][ntg];
        #pragma unroll
        for(int e = 0; e < 4; e++){
          int i = mt*4 + e;
          int du = dupc((uint32_t)(qbp_r[i] ^ kbp_c[ntg]));
          float ein  = __expf(fmaf(C_TEMP, s4[e], -lndup(du)) - lse_r[i]);
          float dots = fmaf(-p4[e]*rcpdup(du), pfac_r[i], ein);
          dsump[i] += dots;
          int row = 32*w + 16*mt + 4*quad + e;
          int colL = l15 + 16*nt;
          uint16_t hi = f2bf(dots);
          float lo = dots - bf2f(hi);
          *((uint16_t*)(smem + row*272 + 2*colL)) = hi;
          *((uint16_t*)(smem + row*272 + 128 + 2*colL)) = f2bf(lo);
        }
      }
    }
    // O MFMAs for this k-half (each wave reads only its own D rows -> no barrier needed)
    bf16x8 dhi[2][2], dlo[2][2];
    #pragma unroll
    for(int mt = 0; mt < 2; mt++)
      #pragma unroll
      for(int ks = 0; ks < 2; ks++){
        const char* ap = smem + (32*w + 16*mt + l15)*272 + 64*ks + 16*quad;
        dhi[mt][ks] = *((const bf16x8*)ap);
        dlo[mt][ks] = *((const bf16x8*)(ap + 128));
      }
    #pragma unroll
    for(int nv = 0; nv < 4; nv++){
      #pragma unroll
      for(int ks = 0; ks < 2; ks++){
        const char* bp = smem + OFS_B + (16*nv + l15)*528 + 128*hv + 64*ks + 16*quad;
        bf16x8 vhi = *((const bf16x8*)bp);
        bf16x8 vlo = *((const bf16x8*)(bp + 256));
        #pragma unroll
        for(int mt = 0; mt < 2; mt++){
          acc_o[mt][nv] = __builtin_amdgcn_mfma_f32_16x16x32_bf16(dhi[mt][ks], vhi, acc_o[mt][nv], 0, 0, 0);
          acc_o[mt][nv] = __builtin_amdgcn_mfma_f32_16x16x32_bf16(dhi[mt][ks], vlo, acc_o[mt][nv], 0, 0, 0);
          acc_o[mt][nv] = __builtin_amdgcn_mfma_f32_16x16x32_bf16(dlo[mt][ks], vhi, acc_o[mt][nv], 0, 0, 0);
        }
      }
    }
  }

  // epilogue
  #pragma unroll
  for(int i = 0; i < 8; i++){
    float s = dsump[i];
    s += __shfl_xor(s, 1, 64); s += __shfl_xor(s, 2, 64);
    s += __shfl_xor(s, 4, 64); s += __shfl_xor(s, 8, 64);
    dsump[i] = s;
  }
  size_t obase = ((size_t)h*TBH + bh)*TT;
  if(l15 == 0){
    #pragma unroll
    for(int i = 0; i < 8; i++){
      int r = 32*w + 16*(i >> 2) + 4*quad + (i & 3);
      int tq = qidxL[r];
      lse_t [obase + tq] = lse_r[i];
      dsum_t[obase + tq] = dsump[i];
    }
  }
  #pragma unroll
  for(int mt = 0; mt < 2; mt++){
    #pragma unroll
    for(int e = 0; e < 4; e++){
      int r = 32*w + 16*mt + 4*quad + e;
      int tq = qidxL[r];
      float* orow = o_t + (obase + tq)*64;
      #pragma unroll
      for(int nv = 0; nv < 4; nv++) orow[l15 + 16*nv] = acc_o[mt][nv][e];
    }
  }
}

// ---------------- K7: fused qkv GEMM + hash-round combine (packed qp) ----------------
__launch_bounds__(512, 1)
__global__ void k_final2(const float* __restrict__ qp, const float* __restrict__ kv,
                         const float* __restrict__ ksum, const float* __restrict__ o_t,
                         const float* __restrict__ lse_t, const float* __restrict__ dsum_t,
                         const float* __restrict__ pls, const float* __restrict__ kls,
                         float* __restrict__ out){
  __shared__ __align__(16) float kv_l[256*68];   // [m][d], col 64 = ksum (68.0 KB)
  __shared__ __align__(16) float qp_l[128*68];   // [r][64-m chunk] (34.8 KB)
  __shared__ float prL[128][4];
  __shared__ float pscL[128];
  __shared__ float nrmL[128];
  int tid = threadIdx.x;
  int bx = blockIdx.x; int bh = bx >> 5, ch = bx & 31;
  int b = bh >> 3, hh = bh & 7;
  int t0 = ch*128;
  {
    const float4* kv4 = (const float4*)(kv + (size_t)bh*16384);
    #pragma unroll
    for(int i = 0; i < 8; i++){
      int idx = i*512 + tid;
      int m = idx >> 4, d4 = idx & 15;
      *((float4*)(kv_l + m*68 + d4*4)) = kv4[idx];
    }
    if(tid < 256) kv_l[tid*68 + 64] = ksum[bh*256 + tid];
  }
  int c = tid & 15, tb = tid >> 4;   // c: d-group (4 cols), tb: 0..31
  float4 acc[4];
  #pragma unroll
  for(int tt = 0; tt < 4; tt++) acc[tt] = make_float4(0.f,0.f,0.f,0.f);
  float p1 = 0.f;
  for(int c4 = 0; c4 < 4; c4++){
    __syncthreads();
    #pragma unroll
    for(int it = 0; it < 4; it++){
      int r = it*32 + tb;
      const char* rp = (const char*)qp + ((size_t)bh*TT + t0 + r)*1024 + c4*256 + 8*c;
      uint2 h2 = *((const uint2*)rp);
      uint2 l2 = *((const uint2*)(rp + 128));
      float4 f;
      f.x = bf2f(h2.x & 0xffffu) + bf2f(l2.x & 0xffffu);
      f.y = bf2f(h2.x >> 16)     + bf2f(l2.x >> 16);
      f.z = bf2f(h2.y & 0xffffu) + bf2f(l2.y & 0xffffu);
      f.w = bf2f(h2.y >> 16)     + bf2f(l2.y >> 16);
      *((float4*)(qp_l + r*68 + c*4)) = f;
    }
    __syncthreads();
    #pragma unroll 4
    for(int m4 = 0; m4 < 16; m4++){
      float4 qv[4];
      #pragma unroll
      for(int tt = 0; tt < 4; tt++)
        qv[tt] = *((const float4*)(qp_l + (tb + 32*tt)*68 + m4*4));
      #pragma unroll
      for(int mm = 0; mm < 4; mm++){
        int m = c4*64 + m4*4 + mm;
        float4 kvv = *((const float4*)(kv_l + m*68 + c*4));
        #pragma unroll
        for(int tt = 0; tt < 4; tt++){
          float qs = (mm == 0) ? qv[tt].x : (mm == 1) ? qv[tt].y : (mm == 2) ? qv[tt].z : qv[tt].w;
          acc[tt].x = fmaf(qs, kvv.x, acc[tt].x);
          acc[tt].y = fmaf(qs, kvv.y, acc[tt].y);
          acc[tt].z = fmaf(qs, kvv.z, acc[tt].z);
          acc[tt].w = fmaf(qs, kvv.w, acc[tt].w);
        }
      }
    }
    if(tid < 128){   // p1 partial for row tid over this m-chunk (ascending m)
      #pragma unroll 8
      for(int m = 0; m < 64; m++)
        p1 = fmaf(qp_l[tid*68 + m], kv_l[(c4*64 + m)*68 + 64], p1);
    }
  }
  __syncthreads();
  if(tid < 128){   // per-row combine scalars
    int t = t0 + tid;
    float l0 = lse_t[((size_t)0*TBH + bh)*TT + t], l1 = lse_t[((size_t)1*TBH + bh)*TT + t];
    float l2 = lse_t[((size_t)2*TBH + bh)*TT + t], l3 = lse_t[((size_t)3*TBH + bh)*TT + t];
    float M = fmaxf(fmaxf(l0, l1), fmaxf(l2, l3));
    float e0 = __expf(l0 - M), e1 = __expf(l1 - M), e2 = __expf(l2 - M), e3 = __expf(l3 - M);
    float rs = 1.f / (e0 + e1 + e2 + e3);
    float pr0 = e0*rs, pr1 = e1*rs, pr2 = e2*rs, pr3 = e3*rs;
    float psc = __expf(pls[bh*TT + t] + kls[bh] - M)*rs;
    float nrm = 0.f;
    nrm = fmaf(dsum_t[((size_t)0*TBH + bh)*TT + t], pr0, nrm);
    nrm = fmaf(dsum_t[((size_t)1*TBH + bh)*TT + t], pr1, nrm);
    nrm = fmaf(dsum_t[((size_t)2*TBH + bh)*TT + t], pr2, nrm);
    nrm = fmaf(dsum_t[((size_t)3*TBH + bh)*TT + t], pr3, nrm);
    nrm = fmaf(p1, psc, nrm);
    prL[tid][0] = pr0; prL[tid][1] = pr1; prL[tid][2] = pr2; prL[tid][3] = pr3;
    pscL[tid] = psc;
    nrmL[tid] = fmaxf(nrm, 1e-6f);
  }
  __syncthreads();
  #pragma unroll
  for(int tt = 0; tt < 4; tt++){
    int r = tb + 32*tt; int t = t0 + r;
    float4 o0 = *((const float4*)(o_t + (((size_t)0*TBH + bh)*TT + t)*64 + c*4));
    float4 o1 = *((const float4*)(o_t + (((size_t)1*TBH + bh)*TT + t)*64 + c*4));
    float4 o2 = *((const float4*)(o_t + (((size_t)2*TBH + bh)*TT + t)*64 + c*4));
    float4 o3 = *((const float4*)(o_t + (((size_t)3*TBH + bh)*TT + t)*64 + c*4));
    float pr0 = prL[r][0], pr1 = prL[r][1], pr2 = prL[r][2], pr3 = prL[r][3];
    float psc = pscL[r], nrm = nrmL[r];
    float4 outl;
    outl.x = fmaf(o3.x, pr3, fmaf(o2.x, pr2, fmaf(o1.x, pr1, o0.x*pr0)));
    outl.y = fmaf(o3.y, pr3, fmaf(o2.y, pr2, fmaf(o1.y, pr1, o0.y*pr0)));
    outl.z = fmaf(o3.z, pr3, fmaf(o2.z, pr2, fmaf(o1.z, pr1, o0.z*pr0)));
    outl.w = fmaf(o3.w, pr3, fmaf(o2.w, pr2, fmaf(o1.w, pr1, o0.w*pr0)));
    float4 res;
    res.x = (outl.x + acc[tt].x*psc) / nrm;
    res.y = (outl.y + acc[tt].y*psc) / nrm;
    res.z = (outl.z + acc[tt].z*psc) / nrm;
    res.w = (outl.w + acc[tt].w*psc) / nrm;
    *((float4*)(out + ((size_t)(b*TT + t)*TH + hh)*64 + c*4)) = res;
  }
}

// sentinel: signals ws_size-too-small distinctly from a numeric bug
__global__ void k_sentinel(float* __restrict__ out, int n){
  int i = blockIdx.x*256 + threadIdx.x;
  if(i < n) out[i] = 12345.0f;
}

extern "C" void kernel_launch(void* const* d_in, const int* in_sizes, int n_in,
                              void* d_out, int out_size, void* d_ws, size_t ws_size,
                              hipStream_t stream){
  const float* q     = (const float*)d_in[0];
  const float* k     = (const float*)d_in[1];
  const float* v     = (const float*)d_in[2];
  const float* proj  = (const float*)d_in[3];
  const float* alpha = (const float*)d_in[4];
  const float* beta  = (const float*)d_in[5];
  float* out = (float*)d_out;
  char* ws = (char*)d_ws;

  if(ws_size < WS_NEED){
    k_sentinel<<<dim3((out_size + 255)/256), dim3(256), 0, stream>>>(out, out_size);
    return;
  }

  float*  qn2f  = (float*) (ws + OFF_QN2F);
  float*  kn2f  = (float*) (ws + OFF_KN2F);
  double* qn2d  = (double*)(ws + OFF_QN2D);
  double* kn2d  = (double*)(ws + OFF_KN2D);
  double* mqk2  = (double*)(ws + OFF_MQK2);
  double* qmaxp = (double*)(ws + OFF_QMAXP);
  double* kmaxp = (double*)(ws + OFF_KMAXP);
  double* qh    = (double*)(ws + OFF_QH);
  double* kh    = (double*)(ws + OFF_KH);
  int*   qpos   = (int*)  (ws + OFF_QPOS);
  int*   kpos   = (int*)  (ws + OFF_KPOS);
  int*   qrev   = (int*)  (ws + OFF_QREV);
  int*   krev   = (int*)  (ws + OFF_KREV);
  float* klsp   = (float*)(ws + OFF_KLSP);
  float* kls    = (float*)(ws + OFF_KLS);
  float* qp     = (float*)(ws + OFF_QP);   // dashQ fp32 -> packed hi/lo
  float* kp     = (float*)(ws + OFF_KP);   // dashK fp32 -> packed hi/lo
  float* pls    = (float*)(ws + OFF_PLS);
  float* ksum   = (float*)(ws + OFF_KSUM);
  float* kvv    = (float*)(ws + OFF_KV);
  float* o_t    = (float*)(ws + OFF_OT);
  float* lse_t  = (float*)(ws + OFF_LSET);
  float* dsum_t = (float*)(ws + OFF_DSUM);
  float* kvp    = (float*)(ws + OFF_KVP);  // overlays dead qn2d/kn2d/qh/kh
  float* ksump  = (float*)(ws + OFF_KSP);

  k_norms2<<<dim3(256),   dim3(256),  0, stream>>>(q, k, qn2f, kn2f, qn2d, kn2d, qmaxp, kmaxp);
  k_mqk   <<<dim3(16),    dim3(64),   0, stream>>>(qmaxp, kmaxp, mqk2);
  k_hash  <<<dim3(512),   dim3(256),  0, stream>>>(q, k, alpha, beta, qn2d, kn2d, mqk2, qh, kh);
  k_sort  <<<dim3(128),   dim3(1024), 0, stream>>>(qh, kh, qpos, kpos, qrev, krev);
  k_dash  <<<dim3(1024),  dim3(512),  0, stream>>>(q, k, proj, qn2f, kn2f, qp, kp);
  k_klsmax<<<dim3(2048),  dim3(256),  0, stream>>>(kp, klsp);
  k_klsred<<<dim3(16),    dim3(128),  0, stream>>>(klsp, kls);
  k_expk  <<<dim3(16384), dim3(256),  0, stream>>>(kp, kls);
  k_expq  <<<dim3(16384), dim3(256),  0, stream>>>(qp, pls);
  k_kv2   <<<dim3(512),   dim3(256),  0, stream>>>(kp, v, kvp, ksump);
  k_kvred <<<dim3(257),   dim3(256),  0, stream>>>(kvp, ksump, kvv, ksum);
  k_bucket<<<dim3(2048),  dim3(256),  0, stream>>>(q, k, v, qp, kp, qpos, kpos, qrev, krev, pls, kls, qn2f, kn2f, o_t, lse_t, dsum_t);
  k_final2<<<dim3(512),   dim3(512),  0, stream>>>(qp, kvv, ksum, o_t, lse_t, dsum_t, pls, kls, out);
}

// Round 9
// 805.231 us; speedup vs baseline: 1.1947x; 1.1947x over previous
//
#include <hip/hip_runtime.h>
#include <stdint.h>
#include <math.h>

#define DEVI __device__ __forceinline__

// Problem constants (B,T,H,E fixed by the reference setup)
constexpr int TB  = 2;
constexpr int TT  = 4096;
constexpr int TH  = 8;
constexpr int TE  = 64;
constexpr int TBH = 16;   // B*H
constexpr int TM  = 256;  // performer features
constexpr int TNH = 4;    // hash rounds
constexpr float C_TEMP  = 0.125f;                 // 1/sqrt(E)
constexpr float C_DN    = 0.35355339059327373f;   // sqrt(temp)
constexpr float C_RATIO = 0.0625f;                // M^-0.5

typedef __attribute__((ext_vector_type(8))) short bf16x8;
typedef __attribute__((ext_vector_type(4))) float f32x4;

// ---------------- workspace layout ----------------
constexpr size_t algn(size_t x){ return (x + 255) & ~(size_t)255; }
constexpr size_t OFF_QN2F = 0;
constexpr size_t OFF_KN2F = algn(OFF_QN2F + (size_t)TBH*TT*4);
constexpr size_t OFF_QN2D = algn(OFF_KN2F + (size_t)TBH*TT*4);
constexpr size_t OFF_KN2D = algn(OFF_QN2D + (size_t)TBH*TT*8);
constexpr size_t OFF_MQK2 = algn(OFF_KN2D + (size_t)TBH*TT*8);
constexpr size_t OFF_QMAXP= algn(OFF_MQK2 + (size_t)TBH*8);
constexpr size_t OFF_KMAXP= algn(OFF_QMAXP+ (size_t)TBH*16*8);
constexpr size_t OFF_QH   = algn(OFF_KMAXP+ (size_t)TBH*16*8);
constexpr size_t OFF_KH   = algn(OFF_QH   + (size_t)TNH*TBH*TT*8);
constexpr size_t OFF_QPOS = algn(OFF_KH   + (size_t)TNH*TBH*TT*8);
constexpr size_t OFF_KPOS = algn(OFF_QPOS + (size_t)TNH*TBH*TT*4);
constexpr size_t OFF_QREV = algn(OFF_KPOS + (size_t)TNH*TBH*TT*4);
constexpr size_t OFF_KREV = algn(OFF_QREV + (size_t)TNH*TBH*TT*4);
constexpr size_t OFF_KLSP = algn(OFF_KREV + (size_t)TNH*TBH*TT*4);
constexpr size_t OFF_KLS  = algn(OFF_KLSP + (size_t)TBH*128*4);
constexpr size_t OFF_QP   = algn(OFF_KLS  + (size_t)TBH*4);
constexpr size_t OFF_KP   = algn(OFF_QP   + (size_t)TBH*TT*TM*4);   // fp32
constexpr size_t OFF_PLS  = algn(OFF_KP   + (size_t)TBH*TT*TM*4);   // fp32
constexpr size_t OFF_KSUM = algn(OFF_PLS  + (size_t)TBH*TT*4);
constexpr size_t OFF_KV   = algn(OFF_KSUM + (size_t)TBH*TM*4);
constexpr size_t OFF_OT   = algn(OFF_KV   + (size_t)TBH*TM*TE*4);   // fp32
constexpr size_t OFF_LSET = algn(OFF_OT   + (size_t)TNH*TBH*TT*TE*4);
constexpr size_t OFF_DSUM = algn(OFF_LSET + (size_t)TNH*TBH*TT*4);
constexpr size_t WS_NEED  = algn(OFF_DSUM + (size_t)TNH*TBH*TT*4);  // ~203 MB
// overlays (dead after k_sort/k_hash): kv partials in qn2d..kh window
constexpr size_t OFF_KVP  = OFF_QN2D;                  // 4 MB
constexpr size_t OFF_KSP  = OFF_KVP + (size_t)4*16*256*64*4;  // 64 KB

// ---------------- helpers ----------------
DEVI float bf2f(uint32_t u16){ uint32_t x = u16 << 16; return __builtin_bit_cast(float, x); }
DEVI uint16_t f2bf(float f){
  uint32_t x = __builtin_bit_cast(uint32_t, f);
  uint32_t r = x + 0x7fffu + ((x >> 16) & 1u);   // RNE
  return (uint16_t)(r >> 16);
}
DEVI int dupc(uint32_t x){
  return (int)((x & 0xffu) == 0) + (int)(((x >> 8) & 0xffu) == 0)
       + (int)(((x >> 16) & 0xffu) == 0) + (int)((x >> 24) == 0);
}
DEVI float lndup(int d){
  return d == 1 ? 0.f : d == 2 ? 0.69314718f : d == 3 ? 1.09861229f : 1.38629436f;
}
DEVI float rcpdup(int d){
  return d == 1 ? 1.f : d == 2 ? 0.5f : d == 3 ? 0.333333343f : 0.25f;
}

// stage 32 floats (half of a 64-wide row) as bf16 hi|lo into a 272B LDS row
DEVI void stage64(char* rowp, const float4* src8, int hf){
  #pragma unroll
  for(int x = 0; x < 8; x++){
    float4 vv = src8[x];
    uint16_t hx = f2bf(vv.x), hy = f2bf(vv.y), hz = f2bf(vv.z), hw = f2bf(vv.w);
    float lx = vv.x - bf2f(hx), ly = vv.y - bf2f(hy), lz = vv.z - bf2f(hz), lw = vv.w - bf2f(hw);
    uint2 hp = make_uint2((uint32_t)hx | ((uint32_t)hy << 16), (uint32_t)hz | ((uint32_t)hw << 16));
    uint2 lp = make_uint2((uint32_t)f2bf(lx) | ((uint32_t)f2bf(ly) << 16),
                          (uint32_t)f2bf(lz) | ((uint32_t)f2bf(lw) << 16));
    *((uint2*)(rowp + 64*hf + 8*x)) = hp;
    *((uint2*)(rowp + 128 + 64*hf + 8*x)) = lp;
  }
}

// ---------------- K1: row sumsq (f32+f64) + partial max (XBOX+ ext) ----------------
__global__ void k_norms2(const float* __restrict__ q, const float* __restrict__ kk,
                         float* __restrict__ qn2f, float* __restrict__ kn2f,
                         double* __restrict__ qn2d, double* __restrict__ kn2d,
                         double* __restrict__ qmaxp, double* __restrict__ kmaxp){
  __shared__ double red[256];
  int bx = blockIdx.x; int chunk = bx & 15, bh = bx >> 4;
  int tid = threadIdx.x;
  int b = bh >> 3, hh = bh & 7;
  int t = chunk*256 + tid;
  const float4* r1 = (const float4*)(q + (((size_t)(b*TT + t)*TH) + hh)*TE);
  double s = 0.0;
  #pragma unroll
  for(int x = 0; x < 16; x++){
    float4 vv = r1[x];
    s += (double)vv.x*vv.x + (double)vv.y*vv.y + (double)vv.z*vv.z + (double)vv.w*vv.w;
  }
  qn2d[bh*TT + t] = s; qn2f[bh*TT + t] = (float)s;
  const float4* r2 = (const float4*)(kk + (((size_t)(b*TT + t)*TH) + hh)*TE);
  double s2 = 0.0;
  #pragma unroll
  for(int x = 0; x < 16; x++){
    float4 vv = r2[x];
    s2 += (double)vv.x*vv.x + (double)vv.y*vv.y + (double)vv.z*vv.z + (double)vv.w*vv.w;
  }
  kn2d[bh*TT + t] = s2; kn2f[bh*TT + t] = (float)s2;
  red[tid] = s; __syncthreads();
  for(int o = 128; o > 0; o >>= 1){ if(tid < o) red[tid] = fmax(red[tid], red[tid+o]); __syncthreads(); }
  if(tid == 0) qmaxp[bh*16 + chunk] = red[0];
  __syncthreads();
  red[tid] = s2; __syncthreads();
  for(int o = 128; o > 0; o >>= 1){ if(tid < o) red[tid] = fmax(red[tid], red[tid+o]); __syncthreads(); }
  if(tid == 0) kmaxp[bh*16 + chunk] = red[0];
}

__global__ void k_mqk(const double* __restrict__ qmaxp, const double* __restrict__ kmaxp,
                      double* __restrict__ mqk2){
  int bh = blockIdx.x;
  if(threadIdx.x == 0){
    double mq = -1e300, mk = -1e300;
    for(int i = 0; i < 16; i++){ mq = fmax(mq, qmaxp[bh*16 + i]); mk = fmax(mk, kmaxp[bh*16 + i]); }
    mqk2[bh] = mq + mk;
  }
}

// ---------------- K2: E2LSH hashes (float64) ----------------
__global__ void k_hash(const float* __restrict__ q, const float* __restrict__ kk,
                       const float* __restrict__ alpha, const float* __restrict__ beta,
                       const double* __restrict__ qn2d, const double* __restrict__ kn2d,
                       const double* __restrict__ mqk2,
                       double* __restrict__ qh, double* __restrict__ kh){
  __shared__ double al[264];
  __shared__ double be[4];
  int tid = threadIdx.x;
  for(int i = tid; i < 264; i += 256) al[i] = (double)alpha[i];
  if(tid < 4) be[tid] = (double)beta[tid];
  __syncthreads();
  int gid = blockIdx.x*256 + tid;
  int side = gid >> 16; int r = gid & 65535;
  int bh = r >> 12, t = r & 4095;
  int b = bh >> 3, hh = bh & 7;
  const float* x = (side ? kk : q) + (((size_t)(b*TT + t)*TH) + hh)*TE;
  const float4* xr = (const float4*)x;
  double a0 = 0.0, a1 = 0.0, a2 = 0.0, a3 = 0.0;
  #pragma unroll
  for(int c = 0; c < 16; c++){
    float4 vv = xr[c];
    const double* a = al + c*16;
    a0 += (double)vv.x*a[0]  + (double)vv.y*a[4]  + (double)vv.z*a[8]  + (double)vv.w*a[12];
    a1 += (double)vv.x*a[1]  + (double)vv.y*a[5]  + (double)vv.z*a[9]  + (double)vv.w*a[13];
    a2 += (double)vv.x*a[2]  + (double)vv.y*a[6]  + (double)vv.z*a[10] + (double)vv.w*a[14];
    a3 += (double)vv.x*a[3]  + (double)vv.y*a[7]  + (double)vv.z*a[11] + (double)vv.w*a[15];
  }
  double n2  = (side ? kn2d : qn2d)[bh*TT + t];
  double ext = sqrt(fmax(mqk2[bh] - n2, 0.0));
  int ec = side ? 65 : 64;
  double* dst = side ? kh : qh;
  dst[((size_t)0*TBH + bh)*TT + t] = a0 + ext*al[ec*4 + 0] + be[0];
  dst[((size_t)1*TBH + bh)*TT + t] = a1 + ext*al[ec*4 + 1] + be[1];
  dst[((size_t)2*TBH + bh)*TT + t] = a2 + ext*al[ec*4 + 2] + be[2];
  dst[((size_t)3*TBH + bh)*TT + t] = a3 + ext*al[ec*4 + 3] + be[3];
}

// ---------------- K3: stable argsort via bitonic on doubles (1024 thr) ----------------
__global__ void k_sort(const double* __restrict__ qh, const double* __restrict__ kh,
                       int* __restrict__ qpos, int* __restrict__ kpos,
                       int* __restrict__ qrev, int* __restrict__ krev){
  __shared__ double v[4096];
  __shared__ int    ix[4096];
  int blk = blockIdx.x; int side = blk >> 6; int hb = blk & 63;
  const double* src = (side ? kh : qh) + (size_t)hb*TT;
  int tid = threadIdx.x;
  for(int i = tid; i < 4096; i += 1024){ v[i] = src[i]; ix[i] = i; }
  __syncthreads();
  for(int k = 2; k <= 4096; k <<= 1){
    for(int j = k >> 1; j > 0; j >>= 1){
      for(int i = tid; i < 4096; i += 1024){
        int l = i ^ j;
        if(l > i){
          double va = v[i], vb = v[l]; int ia = ix[i], ib = ix[l];
          bool gt  = (va > vb) || (va == vb && ia > ib);
          bool asc = ((i & k) == 0);
          if(gt == asc){ v[i] = vb; v[l] = va; ix[i] = ib; ix[l] = ia; }
        }
      }
      __syncthreads();
    }
  }
  int* pos = (side ? kpos : qpos) + (size_t)hb*TT;
  int* rev = (side ? krev : qrev) + (size_t)hb*TT;
  for(int i = tid; i < 4096; i += 1024){ int id = ix[i]; pos[i] = id; rev[id] = i; }
}

// ---------------- K4: dash GEMM + fused q-side exp / k-side block max ----------------
// side=0: qp = exp(dash - rowmax)*ratio (written directly), pls = rowmax.
// side=1: kdash written raw; block max -> klsp[bh*32+ch].
// fp32 chains bit-identical to the R6 k_dash + k_expq + k_klsmax pipeline.
__launch_bounds__(512, 1)
__global__ void k_dash(const float* __restrict__ q, const float* __restrict__ kk,
                       const float* __restrict__ proj,
                       const float* __restrict__ qn2f, const float* __restrict__ kn2f,
                       float* __restrict__ qp, float* __restrict__ kdash,
                       float* __restrict__ klsp, float* __restrict__ pls){
  __shared__ __align__(16) float pjL[64*260];    // 66.6 KB
  __shared__ __align__(16) float x_l[128*68];    // 34.8 KB
  __shared__ float x_n[128];
  __shared__ float wred8[8];
  int tid = threadIdx.x;
  int bx = blockIdx.x;
  int side = bx >> 9; int r = bx & 511; int bh = r >> 5; int ch = r & 31;
  int b = bh >> 3, hh = bh & 7, t0 = ch*128;
  const float* x  = side ? kk   : q;
  const float* n2 = side ? kn2f : qn2f;

  #pragma unroll 8
  for(int it = 0; it < 32; it++){
    int idx = it*512 + tid;
    pjL[(idx & 63)*260 + (idx >> 6)] = proj[idx];
  }
  {
    int rr = tid >> 2, c = tid & 3;
    const float4* src = (const float4*)(x + (((size_t)(b*TT + t0 + rr)*TH) + hh)*TE);
    float4* dst = (float4*)(x_l + rr*68);
    #pragma unroll
    for(int i = 0; i < 4; i++) dst[c*4 + i] = src[c*4 + i];
  }
  if(tid < 128) x_n[tid] = n2[bh*TT + t0 + tid];
  __syncthreads();

  int ml = (tid & 15)*4;
  int tb = tid >> 4;   // 0..31
  float4 acc[4][4];
  #pragma unroll
  for(int tt = 0; tt < 4; tt++)
    #pragma unroll
    for(int g = 0; g < 4; g++) acc[tt][g] = make_float4(0.f,0.f,0.f,0.f);

  #pragma unroll 4
  for(int k4 = 0; k4 < 16; k4++){
    float4 xv[4];
    #pragma unroll
    for(int tt = 0; tt < 4; tt++)
      xv[tt] = *((const float4*)(x_l + (tb + 32*tt)*68 + k4*4));
    #pragma unroll
    for(int kk4 = 0; kk4 < 4; kk4++){
      int krow = k4*4 + kk4;
      #pragma unroll
      for(int g = 0; g < 4; g++){
        float4 pv = *((const float4*)(pjL + krow*260 + ml + 64*g));
        #pragma unroll
        for(int tt = 0; tt < 4; tt++){
          float xs = (kk4 == 0) ? xv[tt].x : (kk4 == 1) ? xv[tt].y : (kk4 == 2) ? xv[tt].z : xv[tt].w;
          acc[tt][g].x = fmaf(xs, pv.x, acc[tt][g].x);
          acc[tt][g].y = fmaf(xs, pv.y, acc[tt][g].y);
          acc[tt][g].z = fmaf(xs, pv.z, acc[tt][g].z);
          acc[tt][g].w = fmaf(xs, pv.w, acc[tt][g].w);
        }
      }
    }
  }

  if(side == 0){
    #pragma unroll
    for(int tt = 0; tt < 4; tt++){
      int t_r = tb + 32*tt;
      float diag = 0.5f*C_TEMP*x_n[t_r];
      float dd[4][4];
      float mx = -1e30f;
      #pragma unroll
      for(int g = 0; g < 4; g++){
        float4 a = acc[tt][g];
        dd[g][0] = fmaf(C_DN, a.x, -diag); dd[g][1] = fmaf(C_DN, a.y, -diag);
        dd[g][2] = fmaf(C_DN, a.z, -diag); dd[g][3] = fmaf(C_DN, a.w, -diag);
        mx = fmaxf(mx, fmaxf(fmaxf(dd[g][0], dd[g][1]), fmaxf(dd[g][2], dd[g][3])));
      }
      // 16 threads (same tb, wave-contiguous) own this row -> shfl row max
      #pragma unroll
      for(int s = 1; s < 16; s <<= 1) mx = fmaxf(mx, __shfl_xor(mx, s, 64));
      size_t rowbase = ((size_t)bh*TT + t0 + t_r)*256;
      #pragma unroll
      for(int g = 0; g < 4; g++){
        float4 e;
        e.x = __expf(dd[g][0] - mx)*C_RATIO; e.y = __expf(dd[g][1] - mx)*C_RATIO;
        e.z = __expf(dd[g][2] - mx)*C_RATIO; e.w = __expf(dd[g][3] - mx)*C_RATIO;
        *((float4*)(qp + rowbase + ml + 64*g)) = e;
      }
      if((tid & 15) == 0) pls[(size_t)bh*TT + t0 + t_r] = mx;
    }
  } else {
    float mx = -1e30f;
    #pragma unroll
    for(int tt = 0; tt < 4; tt++){
      int t_r = tb + 32*tt;
      float diag = 0.5f*C_TEMP*x_n[t_r];
      size_t rowbase = ((size_t)bh*TT + t0 + t_r)*256;
      #pragma unroll
      for(int g = 0; g < 4; g++){
        float4 a = acc[tt][g];
        float4 dd;
        dd.x = fmaf(C_DN, a.x, -diag); dd.y = fmaf(C_DN, a.y, -diag);
        dd.z = fmaf(C_DN, a.z, -diag); dd.w = fmaf(C_DN, a.w, -diag);
        *((float4*)(kdash + rowbase + ml + 64*g)) = dd;
        mx = fmaxf(mx, fmaxf(fmaxf(dd.x, dd.y), fmaxf(dd.z, dd.w)));
      }
    }
    #pragma unroll
    for(int s = 32; s > 0; s >>= 1) mx = fmaxf(mx, __shfl_xor(mx, s, 64));
    if((tid & 63) == 0) wred8[tid >> 6] = mx;
    __syncthreads();
    if(tid == 0){
      float m = wred8[0];
      #pragma unroll
      for(int i = 1; i < 8; i++) m = fmaxf(m, wred8[i]);
      klsp[bh*32 + ch] = m;
    }
  }
}

__global__ void k_klsred(const float* __restrict__ klsp, float* __restrict__ kls){
  int bh = blockIdx.x, tid = threadIdx.x;   // 64 threads
  float v = (tid < 32) ? klsp[bh*32 + tid] : -1e30f;
  #pragma unroll
  for(int o = 16; o > 0; o >>= 1) v = fmaxf(v, __shfl_xor(v, o, 64));
  if(tid == 0) kls[bh] = v;
}

// ---------------- K4c: kp = exp(dashK - kls)*ratio, in place (fp32) ----------------
__global__ void k_expk(float* __restrict__ kp, const float* __restrict__ kls){
  int tid = threadIdx.x; int blk = blockIdx.x;
  float4* p = (float4*)kp;
  size_t base = (size_t)blk*2048;
  float stab = kls[blk >> 7];
  #pragma unroll
  for(int i = 0; i < 8; i++){
    size_t ix = base + i*256 + tid;
    float4 vv = p[ix];
    vv.x = __expf(vv.x - stab)*C_RATIO; vv.y = __expf(vv.y - stab)*C_RATIO;
    vv.z = __expf(vv.z - stab)*C_RATIO; vv.w = __expf(vv.w - stab)*C_RATIO;
    p[ix] = vv;
  }
}

// ---------------- K5: kv partials over s-chunks, then reduce ----------------
__global__ void k_kv2(const float* __restrict__ kp, const float* __restrict__ v,
                      float* __restrict__ kvp, float* __restrict__ ksump){
  int bx = blockIdx.x; int sc = bx >> 7; int rem = bx & 127; int bh = rem >> 3; int mt = rem & 7;
  int tid = threadIdx.x; int g = tid >> 6, d = tid & 63;
  int b = bh >> 3, hh = bh & 7; int m0 = mt*32;
  float a[8], sa[8];
  #pragma unroll
  for(int j = 0; j < 8; j++){ a[j] = 0.f; sa[j] = 0.f; }
  const float* kpb = kp + (size_t)bh*TT*256 + m0 + g;
  const float* vb  = v + (size_t)b*TT*TH*TE + hh*TE + d;
  int s0 = sc*1024;
  #pragma unroll 4
  for(int s = s0; s < s0 + 1024; s++){
    float vv = vb[(size_t)s*512];
    const float* kr = kpb + (size_t)s*256;
    #pragma unroll
    for(int j = 0; j < 8; j++){
      float kj = kr[4*j];
      a[j] = fmaf(kj, vv, a[j]); sa[j] += kj;
    }
  }
  #pragma unroll
  for(int j = 0; j < 8; j++){
    int m = m0 + g + 4*j;
    kvp[(((size_t)sc*16 + bh)*256 + m)*64 + d] = a[j];
    if(d == 0) ksump[((size_t)sc*16 + bh)*256 + m] = sa[j];
  }
}

__global__ void k_kvred(const float* __restrict__ kvp, const float* __restrict__ ksump,
                        float* __restrict__ kv, float* __restrict__ ksum){
  int bx = blockIdx.x, tid = threadIdx.x;
  if(bx < 256){
    size_t i = (size_t)bx*1024 + tid*4;
    float4 s = make_float4(0.f,0.f,0.f,0.f);
    #pragma unroll
    for(int sc = 0; sc < 4; sc++){
      float4 p = *((const float4*)(kvp + (size_t)sc*262144 + i));
      s.x += p.x; s.y += p.y; s.z += p.z; s.w += p.w;
    }
    *((float4*)(kv + i)) = s;
  } else {
    for(int m = tid; m < 4096; m += 256){
      float s = 0.f;
      #pragma unroll
      for(int sc = 0; sc < 4; sc++) s += ksump[sc*4096 + m];
      ksum[m] = s;
    }
  }
}

// ---------------- K6: per-bucket attention, MFMA split-bf16 (R6 structure) ----------------
__launch_bounds__(256, 2)
__global__ void k_bucket(const float* __restrict__ q, const float* __restrict__ kk, const float* __restrict__ v,
                         const float* __restrict__ qp, const float* __restrict__ kp,
                         const int* __restrict__ qpos, const int* __restrict__ kpos,
                         const int* __restrict__ qrev, const int* __restrict__ krev,
                         const float* __restrict__ pls, const float* __restrict__ kls,
                         const float* __restrict__ qn2f, const float* __restrict__ kn2f,
                         float* __restrict__ o_t, float* __restrict__ lse_t, float* __restrict__ dsum_t){
  __shared__ __align__(16) char smem[73232];
  constexpr int OFS_B = 34816;
  int* qidxL   = (int*)(smem + 69632);
  int* kidxL   = (int*)(smem + 70144);
  int* qbpL    = (int*)(smem + 70656);
  int* kbpL    = (int*)(smem + 71168);
  float* lseL  = (float*)(smem + 71680);
  float* pfacL = (float*)(smem + 72192);
  float* kn2L  = (float*)(smem + 72704);
  float* kmaxP = (float*)(smem + 73216);

  int tid = threadIdx.x;
  int w = tid >> 6, lane = tid & 63, l15 = lane & 15, quad = lane >> 4;
  int bx = blockIdx.x; int n = bx & 31, bh = (bx >> 5) & 15, h = bx >> 9;
  int b = bh >> 3, hh = bh & 7;

  if(tid < 128){
    int tk = kpos[((size_t)h*TBH + bh)*TT + n*128 + tid];
    kidxL[tid] = tk;
    int pk = 0;
    #pragma unroll
    for(int h3 = 0; h3 < 4; h3++){ int rv = krev[((size_t)h3*TBH + bh)*TT + tk]; pk |= (rv >> 7) << (8*h3); }
    kbpL[tid] = pk;
    kn2L[tid] = kn2f[(size_t)bh*TT + tk];
    int tq = qpos[((size_t)h*TBH + bh)*TT + n*128 + tid];
    qidxL[tid] = tq;
    int pq = 0;
    #pragma unroll
    for(int h3 = 0; h3 < 4; h3++){ int rv = qrev[((size_t)h3*TBH + bh)*TT + tq]; pq |= (rv >> 7) << (8*h3); }
    qbpL[tid] = pq;
  }
  __syncthreads();
  if(tid < 64){
    float m = fmaxf(kn2L[tid], kn2L[tid + 64]);
    #pragma unroll
    for(int o = 32; o > 0; o >>= 1) m = fmaxf(m, __shfl_xor(m, o, 64));
    if(tid == 0) kmaxP[0] = m;
  }
  {  // stage Q into bufA, K into bufB (fp32 -> bf16 hi/lo)
    int r = tid >> 1, hf = tid & 1;
    const float4* qs = (const float4*)(q  + (((size_t)(b*TT + qidxL[r])*TH) + hh)*TE) + hf*8;
    const float4* ks = (const float4*)(kk + (((size_t)(b*TT + kidxL[r])*TH) + hh)*TE) + hf*8;
    stage64(smem + r*272, qs, hf);
    stage64(smem + OFS_B + r*272, ks, hf);
  }
  __syncthreads();
  if(tid < 128){  // per-row stabilizer (Cauchy-Schwarz UB) + pfac
    int tq = qidxL[tid];
    float plsv = pls[(size_t)bh*TT + tq] + kls[bh];
    float lse = fmaxf(plsv, C_TEMP * sqrtf(qn2f[(size_t)bh*TT + tq] * kmaxP[0]));
    lseL[tid] = lse;
    pfacL[tid] = __expf(plsv - lse);
  }

  f32x4 acc_s[2][8], acc_p[2][8];
  #pragma unroll
  for(int mt = 0; mt < 2; mt++)
    #pragma unroll
    for(int nt = 0; nt < 8; nt++){
      acc_s[mt][nt] = (f32x4){0.f,0.f,0.f,0.f};
      acc_p[mt][nt] = (f32x4){0.f,0.f,0.f,0.f};
    }

  {  // S = Q K^T (K=64, split-3)
    bf16x8 ahi[2][2], alo[2][2];
    #pragma unroll
    for(int mt = 0; mt < 2; mt++)
      #pragma unroll
      for(int ks = 0; ks < 2; ks++){
        const char* ap = smem + (32*w + 16*mt + l15)*272 + 64*ks + 16*quad;
        ahi[mt][ks] = *((const bf16x8*)ap);
        alo[mt][ks] = *((const bf16x8*)(ap + 128));
      }
    #pragma unroll
    for(int nt = 0; nt < 8; nt++){
      #pragma unroll
      for(int ks = 0; ks < 2; ks++){
        const char* bp = smem + OFS_B + (16*nt + l15)*272 + 64*ks + 16*quad;
        bf16x8 bhi = *((const bf16x8*)bp);
        bf16x8 blo = *((const bf16x8*)(bp + 128));
        #pragma unroll
        for(int mt = 0; mt < 2; mt++){
          acc_s[mt][nt] = __builtin_amdgcn_mfma_f32_16x16x32_bf16(ahi[mt][ks], bhi, acc_s[mt][nt], 0, 0, 0);
          acc_s[mt][nt] = __builtin_amdgcn_mfma_f32_16x16x32_bf16(ahi[mt][ks], blo, acc_s[mt][nt], 0, 0, 0);
          acc_s[mt][nt] = __builtin_amdgcn_mfma_f32_16x16x32_bf16(alo[mt][ks], bhi, acc_s[mt][nt], 0, 0, 0);
        }
      }
    }
  }
  __syncthreads();

  // DP = QP KP^T (K=256 in 4 chunks of 64, split-3) — fp32 source + conversion
  for(int c = 0; c < 4; c++){
    { int r = tid >> 1, hf = tid & 1;
      const float4* qs = (const float4*)(qp + ((size_t)bh*TT + qidxL[r])*256 + c*64) + hf*8;
      const float4* ks = (const float4*)(kp + ((size_t)bh*TT + kidxL[r])*256 + c*64) + hf*8;
      stage64(smem + r*272, qs, hf);
      stage64(smem + OFS_B + r*272, ks, hf);
    }
    __syncthreads();
    bf16x8 ahi[2][2], alo[2][2];
    #pragma unroll
    for(int mt = 0; mt < 2; mt++)
      #pragma unroll
      for(int ks = 0; ks < 2; ks++){
        const char* ap = smem + (32*w + 16*mt + l15)*272 + 64*ks + 16*quad;
        ahi[mt][ks] = *((const bf16x8*)ap);
        alo[mt][ks] = *((const bf16x8*)(ap + 128));
      }
    #pragma unroll
    for(int nt = 0; nt < 8; nt++){
      #pragma unroll
      for(int ks = 0; ks < 2; ks++){
        const char* bp = smem + OFS_B + (16*nt + l15)*272 + 64*ks + 16*quad;
        bf16x8 bhi = *((const bf16x8*)bp);
        bf16x8 blo = *((const bf16x8*)(bp + 128));
        #pragma unroll
        for(int mt = 0; mt < 2; mt++){
          acc_p[mt][nt] = __builtin_amdgcn_mfma_f32_16x16x32_bf16(ahi[mt][ks], bhi, acc_p[mt][nt], 0, 0, 0);
          acc_p[mt][nt] = __builtin_amdgcn_mfma_f32_16x16x32_bf16(ahi[mt][ks], blo, acc_p[mt][nt], 0, 0, 0);
          acc_p[mt][nt] = __builtin_amdgcn_mfma_f32_16x16x32_bf16(alo[mt][ks], bhi, acc_p[mt][nt], 0, 0, 0);
        }
      }
    }
    __syncthreads();
  }

  {  // stage V^T into bufB (bf16 hi/lo, transposed)
    int j = tid >> 1, hc = tid & 1;
    const float4* vs = (const float4*)(v + (((size_t)(b*TT + kidxL[j])*TH) + hh)*TE) + hc*8;
    #pragma unroll
    for(int x = 0; x < 8; x++){
      float4 vv = vs[x];
      int c0 = hc*32 + 4*x;
      float vals[4] = {vv.x, vv.y, vv.z, vv.w};
      #pragma unroll
      for(int i = 0; i < 4; i++){
        uint16_t hi = f2bf(vals[i]);
        float lo = vals[i] - bf2f(hi);
        *((uint16_t*)(smem + OFS_B + (c0 + i)*528 + 2*j)) = hi;
        *((uint16_t*)(smem + OFS_B + (c0 + i)*528 + 256 + 2*j)) = f2bf(lo);
      }
    }
  }
  int qbp_r[8]; float lse_r[8], pfac_r[8], dsump[8]; int kbp_c[8];
  #pragma unroll
  for(int i = 0; i < 8; i++){
    int r = 32*w + 16*(i >> 2) + 4*quad + (i & 3);
    qbp_r[i] = qbpL[r]; lse_r[i] = lseL[r]; pfac_r[i] = pfacL[r]; dsump[i] = 0.f;
  }
  #pragma unroll
  for(int nt = 0; nt < 8; nt++) kbp_c[nt] = kbpL[l15 + 16*nt];
  __syncthreads();

  // D (elementwise in C-layout regs) -> LDS bf16 hi/lo -> O += D V (two col-halves)
  f32x4 acc_o[2][4];
  #pragma unroll
  for(int mt = 0; mt < 2; mt++)
    #pragma unroll
    for(int nv = 0; nv < 4; nv++) acc_o[mt][nv] = (f32x4){0.f,0.f,0.f,0.f};

  #pragma unroll
  for(int hv = 0; hv < 2; hv++){
    #pragma unroll
    for(int nt = 0; nt < 4; nt++){
      int ntg = 4*hv + nt;
      #pragma unroll
      for(int mt = 0; mt < 2; mt++){
        f32x4 s4 = acc_s[mt][ntg], p4 = acc_p[mt][ntg];
        #pragma unroll
        for(int e = 0; e < 4; e++){
          int i = mt*4 + e;
          int du = dupc((uint32_t)(qbp_r[i] ^ kbp_c[ntg]));
          float ein  = __expf(fmaf(C_TEMP, s4[e], -lndup(du)) - lse_r[i]);
          float dots = fmaf(-p4[e]*rcpdup(du), pfac_r[i], ein);
          dsump[i] += dots;
          int row = 32*w + 16*mt + 4*quad + e;
          int colL = l15 + 16*nt;
          uint16_t hi = f2bf(dots);
          float lo = dots - bf2f(hi);
          *((uint16_t*)(smem + row*272 + 2*colL)) = hi;
          *((uint16_t*)(smem + row*272 + 128 + 2*colL)) = f2bf(lo);
        }
      }
    }
    bf16x8 dhi[2][2], dlo[2][2];
    #pragma unroll
    for(int mt = 0; mt < 2; mt++)
      #pragma unroll
      for(int ks = 0; ks < 2; ks++){
        const char* ap = smem + (32*w + 16*mt + l15)*272 + 64*ks + 16*quad;
        dhi[mt][ks] = *((const bf16x8*)ap);
        dlo[mt][ks] = *((const bf16x8*)(ap + 128));
      }
    #pragma unroll
    for(int nv = 0; nv < 4; nv++){
      #pragma unroll
      for(int ks = 0; ks < 2; ks++){
        const char* bp = smem + OFS_B + (16*nv + l15)*528 + 128*hv + 64*ks + 16*quad;
        bf16x8 vhi = *((const bf16x8*)bp);
        bf16x8 vlo = *((const bf16x8*)(bp + 256));
        #pragma unroll
        for(int mt = 0; mt < 2; mt++){
          acc_o[mt][nv] = __builtin_amdgcn_mfma_f32_16x16x32_bf16(dhi[mt][ks], vhi, acc_o[mt][nv], 0, 0, 0);
          acc_o[mt][nv] = __builtin_amdgcn_mfma_f32_16x16x32_bf16(dhi[mt][ks], vlo, acc_o[mt][nv], 0, 0, 0);
          acc_o[mt][nv] = __builtin_amdgcn_mfma_f32_16x16x32_bf16(dlo[mt][ks], vhi, acc_o[mt][nv], 0, 0, 0);
        }
      }
    }
  }

  // epilogue
  #pragma unroll
  for(int i = 0; i < 8; i++){
    float s = dsump[i];
    s += __shfl_xor(s, 1, 64); s += __shfl_xor(s, 2, 64);
    s += __shfl_xor(s, 4, 64); s += __shfl_xor(s, 8, 64);
    dsump[i] = s;
  }
  size_t obase = ((size_t)h*TBH + bh)*TT;
  if(l15 == 0){
    #pragma unroll
    for(int i = 0; i < 8; i++){
      int r = 32*w + 16*(i >> 2) + 4*quad + (i & 3);
      int tq = qidxL[r];
      lse_t [obase + tq] = lse_r[i];
      dsum_t[obase + tq] = dsump[i];
    }
  }
  #pragma unroll
  for(int mt = 0; mt < 2; mt++){
    #pragma unroll
    for(int e = 0; e < 4; e++){
      int r = 32*w + 16*mt + 4*quad + e;
      int tq = qidxL[r];
      float* orow = o_t + (obase + tq)*64;
      #pragma unroll
      for(int nv = 0; nv < 4; nv++) orow[l15 + 16*nv] = acc_o[mt][nv][e];
    }
  }
}

// ---------------- K7: fused qkv GEMM + hash-round combine ----------------
__launch_bounds__(512, 1)
__global__ void k_final2(const float* __restrict__ qp, const float* __restrict__ kv,
                         const float* __restrict__ ksum, const float* __restrict__ o_t,
                         const float* __restrict__ lse_t, const float* __restrict__ dsum_t,
                         const float* __restrict__ pls, const float* __restrict__ kls,
                         float* __restrict__ out){
  __shared__ __align__(16) float kv_l[256*68];
  __shared__ __align__(16) float qp_l[128*68];
  __shared__ float prL[128][4];
  __shared__ float pscL[128];
  __shared__ float nrmL[128];
  int tid = threadIdx.x;
  int bx = blockIdx.x; int bh = bx >> 5, ch = bx & 31;
  int b = bh >> 3, hh = bh & 7;
  int t0 = ch*128;
  {
    const float4* kv4 = (const float4*)(kv + (size_t)bh*16384);
    #pragma unroll
    for(int i = 0; i < 8; i++){
      int idx = i*512 + tid;
      int m = idx >> 4, d4 = idx & 15;
      *((float4*)(kv_l + m*68 + d4*4)) = kv4[idx];
    }
    if(tid < 256) kv_l[tid*68 + 64] = ksum[bh*256 + tid];
  }
  int c = tid & 15, tb = tid >> 4;
  float4 acc[4];
  #pragma unroll
  for(int tt = 0; tt < 4; tt++) acc[tt] = make_float4(0.f,0.f,0.f,0.f);
  float p1 = 0.f;
  for(int c4 = 0; c4 < 4; c4++){
    __syncthreads();
    #pragma unroll
    for(int it = 0; it < 4; it++){
      int r = it*32 + tb;
      *((float4*)(qp_l + r*68 + c*4)) =
        *((const float4*)(qp + ((size_t)bh*TT + t0 + r)*256 + c4*64 + c*4));
    }
    __syncthreads();
    #pragma unroll 4
    for(int m4 = 0; m4 < 16; m4++){
      float4 qv[4];
      #pragma unroll
      for(int tt = 0; tt < 4; tt++)
        qv[tt] = *((const float4*)(qp_l + (tb + 32*tt)*68 + m4*4));
      #pragma unroll
      for(int mm = 0; mm < 4; mm++){
        int m = c4*64 + m4*4 + mm;
        float4 kvv = *((const float4*)(kv_l + m*68 + c*4));
        #pragma unroll
        for(int tt = 0; tt < 4; tt++){
          float qs = (mm == 0) ? qv[tt].x : (mm == 1) ? qv[tt].y : (mm == 2) ? qv[tt].z : qv[tt].w;
          acc[tt].x = fmaf(qs, kvv.x, acc[tt].x);
          acc[tt].y = fmaf(qs, kvv.y, acc[tt].y);
          acc[tt].z = fmaf(qs, kvv.z, acc[tt].z);
          acc[tt].w = fmaf(qs, kvv.w, acc[tt].w);
        }
      }
    }
    if(tid < 128){
      #pragma unroll 8
      for(int m = 0; m < 64; m++)
        p1 = fmaf(qp_l[tid*68 + m], kv_l[(c4*64 + m)*68 + 64], p1);
    }
  }
  __syncthreads();
  if(tid < 128){
    int t = t0 + tid;
    float l0 = lse_t[((size_t)0*TBH + bh)*TT + t], l1 = lse_t[((size_t)1*TBH + bh)*TT + t];
    float l2 = lse_t[((size_t)2*TBH + bh)*TT + t], l3 = lse_t[((size_t)3*TBH + bh)*TT + t];
    float M = fmaxf(fmaxf(l0, l1), fmaxf(l2, l3));
    float e0 = __expf(l0 - M), e1 = __expf(l1 - M), e2 = __expf(l2 - M), e3 = __expf(l3 - M);
    float rs = 1.f / (e0 + e1 + e2 + e3);
    float pr0 = e0*rs, pr1 = e1*rs, pr2 = e2*rs, pr3 = e3*rs;
    float psc = __expf(pls[bh*TT + t] + kls[bh] - M)*rs;
    float nrm = 0.f;
    nrm = fmaf(dsum_t[((size_t)0*TBH + bh)*TT + t], pr0, nrm);
    nrm = fmaf(dsum_t[((size_t)1*TBH + bh)*TT + t], pr1, nrm);
    nrm = fmaf(dsum_t[((size_t)2*TBH + bh)*TT + t], pr2, nrm);
    nrm = fmaf(dsum_t[((size_t)3*TBH + bh)*TT + t], pr3, nrm);
    nrm = fmaf(p1, psc, nrm);
    prL[tid][0] = pr0; prL[tid][1] = pr1; prL[tid][2] = pr2; prL[tid][3] = pr3;
    pscL[tid] = psc;
    nrmL[tid] = fmaxf(nrm, 1e-6f);
  }
  __syncthreads();
  #pragma unroll
  for(int tt = 0; tt < 4; tt++){
    int r = tb + 32*tt; int t = t0 + r;
    float4 o0 = *((const float4*)(o_t + (((size_t)0*TBH + bh)*TT + t)*64 + c*4));
    float4 o1 = *((const float4*)(o_t + (((size_t)1*TBH + bh)*TT + t)*64 + c*4));
    float4 o2 = *((const float4*)(o_t + (((size_t)2*TBH + bh)*TT + t)*64 + c*4));
    float4 o3 = *((const float4*)(o_t + (((size_t)3*TBH + bh)*TT + t)*64 + c*4));
    float pr0 = prL[r][0], pr1 = prL[r][1], pr2 = prL[r][2], pr3 = prL[r][3];
    float psc = pscL[r], nrm = nrmL[r];
    float4 outl;
    outl.x = fmaf(o3.x, pr3, fmaf(o2.x, pr2, fmaf(o1.x, pr1, o0.x*pr0)));
    outl.y = fmaf(o3.y, pr3, fmaf(o2.y, pr2, fmaf(o1.y, pr1, o0.y*pr0)));
    outl.z = fmaf(o3.z, pr3, fmaf(o2.z, pr2, fmaf(o1.z, pr1, o0.z*pr0)));
    outl.w = fmaf(o3.w, pr3, fmaf(o2.w, pr2, fmaf(o1.w, pr1, o0.w*pr0)));
    float4 res;
    res.x = (outl.x + acc[tt].x*psc) / nrm;
    res.y = (outl.y + acc[tt].y*psc) / nrm;
    res.z = (outl.z + acc[tt].z*psc) / nrm;
    res.w = (outl.w + acc[tt].w*psc) / nrm;
    *((float4*)(out + ((size_t)(b*TT + t)*TH + hh)*64 + c*4)) = res;
  }
}

// sentinel: signals ws_size-too-small distinctly from a numeric bug
__global__ void k_sentinel(float* __restrict__ out, int n){
  int i = blockIdx.x*256 + threadIdx.x;
  if(i < n) out[i] = 12345.0f;
}

extern "C" void kernel_launch(void* const* d_in, const int* in_sizes, int n_in,
                              void* d_out, int out_size, void* d_ws, size_t ws_size,
                              hipStream_t stream){
  const float* q     = (const float*)d_in[0];
  const float* k     = (const float*)d_in[1];
  const float* v     = (const float*)d_in[2];
  const float* proj  = (const float*)d_in[3];
  const float* alpha = (const float*)d_in[4];
  const float* beta  = (const float*)d_in[5];
  float* out = (float*)d_out;
  char* ws = (char*)d_ws;

  if(ws_size < WS_NEED){
    k_sentinel<<<dim3((out_size + 255)/256), dim3(256), 0, stream>>>(out, out_size);
    return;
  }

  float*  qn2f  = (float*) (ws + OFF_QN2F);
  float*  kn2f  = (float*) (ws + OFF_KN2F);
  double* qn2d  = (double*)(ws + OFF_QN2D);
  double* kn2d  = (double*)(ws + OFF_KN2D);
  double* mqk2  = (double*)(ws + OFF_MQK2);
  double* qmaxp = (double*)(ws + OFF_QMAXP);
  double* kmaxp = (double*)(ws + OFF_KMAXP);
  double* qh    = (double*)(ws + OFF_QH);
  double* kh    = (double*)(ws + OFF_KH);
  int*   qpos   = (int*)  (ws + OFF_QPOS);
  int*   kpos   = (int*)  (ws + OFF_KPOS);
  int*   qrev   = (int*)  (ws + OFF_QREV);
  int*   krev   = (int*)  (ws + OFF_KREV);
  float* klsp   = (float*)(ws + OFF_KLSP);
  float* kls    = (float*)(ws + OFF_KLS);
  float* qp     = (float*)(ws + OFF_QP);
  float* kp     = (float*)(ws + OFF_KP);
  float* pls    = (float*)(ws + OFF_PLS);
  float* ksum   = (float*)(ws + OFF_KSUM);
  float* kvv    = (float*)(ws + OFF_KV);
  float* o_t    = (float*)(ws + OFF_OT);
  float* lse_t  = (float*)(ws + OFF_LSET);
  float* dsum_t = (float*)(ws + OFF_DSUM);
  float* kvp    = (float*)(ws + OFF_KVP);
  float* ksump  = (float*)(ws + OFF_KSP);

  k_norms2<<<dim3(256),   dim3(256),  0, stream>>>(q, k, qn2f, kn2f, qn2d, kn2d, qmaxp, kmaxp);
  k_mqk   <<<dim3(16),    dim3(64),   0, stream>>>(qmaxp, kmaxp, mqk2);
  k_hash  <<<dim3(512),   dim3(256),  0, stream>>>(q, k, alpha, beta, qn2d, kn2d, mqk2, qh, kh);
  k_sort  <<<dim3(128),   dim3(1024), 0, stream>>>(qh, kh, qpos, kpos, qrev, krev);
  k_dash  <<<dim3(1024),  dim3(512),  0, stream>>>(q, k, proj, qn2f, kn2f, qp, kp, klsp, pls);
  k_klsred<<<dim3(16),    dim3(64),   0, stream>>>(klsp, kls);
  k_expk  <<<dim3(2048),  dim3(256),  0, stream>>>(kp, kls);
  k_kv2   <<<dim3(512),   dim3(256),  0, stream>>>(kp, v, kvp, ksump);
  k_kvred <<<dim3(257),   dim3(256),  0, stream>>>(kvp, ksump, kvv, ksum);
  k_bucket<<<dim3(2048),  dim3(256),  0, stream>>>(q, k, v, qp, kp, qpos, kpos, qrev, krev, pls, kls, qn2f, kn2f, o_t, lse_t, dsum_t);
  k_final2<<<dim3(512),   dim3(512),  0, stream>>>(qp, kvv, ksum, o_t, lse_t, dsum_t, pls, kls, out);
}

// Round 10
// 776.951 us; speedup vs baseline: 1.2382x; 1.0364x over previous
//
#include <hip/hip_runtime.h>
#include <stdint.h>
#include <math.h>

#define DEVI __device__ __forceinline__

// Problem constants (B,T,H,E fixed by the reference setup)
constexpr int TB  = 2;
constexpr int TT  = 4096;
constexpr int TH  = 8;
constexpr int TE  = 64;
constexpr int TBH = 16;   // B*H
constexpr int TM  = 256;  // performer features
constexpr int TNH = 4;    // hash rounds
constexpr float C_TEMP  = 0.125f;                 // 1/sqrt(E)
constexpr float C_DN    = 0.35355339059327373f;   // sqrt(temp)
constexpr float C_RATIO = 0.0625f;                // M^-0.5

typedef __attribute__((ext_vector_type(8))) short bf16x8;
typedef __attribute__((ext_vector_type(4))) float f32x4;

// ---------------- workspace layout ----------------
constexpr size_t algn(size_t x){ return (x + 255) & ~(size_t)255; }
constexpr size_t OFF_QN2F = 0;
constexpr size_t OFF_KN2F = algn(OFF_QN2F + (size_t)TBH*TT*4);
constexpr size_t OFF_QN2D = algn(OFF_KN2F + (size_t)TBH*TT*4);
constexpr size_t OFF_KN2D = algn(OFF_QN2D + (size_t)TBH*TT*8);
constexpr size_t OFF_MQK2 = algn(OFF_KN2D + (size_t)TBH*TT*8);
constexpr size_t OFF_QMAXP= algn(OFF_MQK2 + (size_t)TBH*8);
constexpr size_t OFF_KMAXP= algn(OFF_QMAXP+ (size_t)TBH*16*8);
constexpr size_t OFF_QH   = algn(OFF_KMAXP+ (size_t)TBH*16*8);
constexpr size_t OFF_KH   = algn(OFF_QH   + (size_t)TNH*TBH*TT*8);
constexpr size_t OFF_QPOS = algn(OFF_KH   + (size_t)TNH*TBH*TT*8);
constexpr size_t OFF_KPOS = algn(OFF_QPOS + (size_t)TNH*TBH*TT*4);
constexpr size_t OFF_QREV = algn(OFF_KPOS + (size_t)TNH*TBH*TT*4);
constexpr size_t OFF_KREV = algn(OFF_QREV + (size_t)TNH*TBH*TT*4);
constexpr size_t OFF_KLSP = algn(OFF_KREV + (size_t)TNH*TBH*TT*4);
constexpr size_t OFF_KLS  = algn(OFF_KLSP + (size_t)TBH*128*4);
constexpr size_t OFF_QP   = algn(OFF_KLS  + (size_t)TBH*4);
constexpr size_t OFF_KP   = algn(OFF_QP   + (size_t)TBH*TT*TM*4);   // fp32
constexpr size_t OFF_PLS  = algn(OFF_KP   + (size_t)TBH*TT*TM*4);   // fp32
constexpr size_t OFF_KSUM = algn(OFF_PLS  + (size_t)TBH*TT*4);
constexpr size_t OFF_KV   = algn(OFF_KSUM + (size_t)TBH*TM*4);
constexpr size_t OFF_OT   = algn(OFF_KV   + (size_t)TBH*TM*TE*4);   // fp32
constexpr size_t OFF_LSET = algn(OFF_OT   + (size_t)TNH*TBH*TT*TE*4);
constexpr size_t OFF_DSUM = algn(OFF_LSET + (size_t)TNH*TBH*TT*4);
constexpr size_t WS_NEED  = algn(OFF_DSUM + (size_t)TNH*TBH*TT*4);  // ~203 MB
// overlays (dead after k_sort/k_hash): kv partials in qn2d..kh window
constexpr size_t OFF_KVP  = OFF_QN2D;                  // 4 MB
constexpr size_t OFF_KSP  = OFF_KVP + (size_t)4*16*256*64*4;  // 64 KB

// ---------------- helpers ----------------
DEVI float bf2f(uint32_t u16){ uint32_t x = u16 << 16; return __builtin_bit_cast(float, x); }
DEVI uint16_t f2bf(float f){
  uint32_t x = __builtin_bit_cast(uint32_t, f);
  uint32_t r = x + 0x7fffu + ((x >> 16) & 1u);   // RNE
  return (uint16_t)(r >> 16);
}
DEVI int dupc(uint32_t x){
  return (int)((x & 0xffu) == 0) + (int)(((x >> 8) & 0xffu) == 0)
       + (int)(((x >> 16) & 0xffu) == 0) + (int)((x >> 24) == 0);
}
DEVI float lndup(int d){
  return d == 1 ? 0.f : d == 2 ? 0.69314718f : d == 3 ? 1.09861229f : 1.38629436f;
}
DEVI float rcpdup(int d){
  return d == 1 ? 1.f : d == 2 ? 0.5f : d == 3 ? 0.333333343f : 0.25f;
}

// stage 32 floats (half of a 64-wide row) as bf16 hi|lo into a 272B LDS row
DEVI void stage64(char* rowp, const float4* src8, int hf){
  #pragma unroll
  for(int x = 0; x < 8; x++){
    float4 vv = src8[x];
    uint16_t hx = f2bf(vv.x), hy = f2bf(vv.y), hz = f2bf(vv.z), hw = f2bf(vv.w);
    float lx = vv.x - bf2f(hx), ly = vv.y - bf2f(hy), lz = vv.z - bf2f(hz), lw = vv.w - bf2f(hw);
    uint2 hp = make_uint2((uint32_t)hx | ((uint32_t)hy << 16), (uint32_t)hz | ((uint32_t)hw << 16));
    uint2 lp = make_uint2((uint32_t)f2bf(lx) | ((uint32_t)f2bf(ly) << 16),
                          (uint32_t)f2bf(lz) | ((uint32_t)f2bf(lw) << 16));
    *((uint2*)(rowp + 64*hf + 8*x)) = hp;
    *((uint2*)(rowp + 128 + 64*hf + 8*x)) = lp;
  }
}
// same, from registers
DEVI void stage64r(char* rowp, const float4* vv8, int hf){
  #pragma unroll
  for(int x = 0; x < 8; x++){
    float4 vv = vv8[x];
    uint16_t hx = f2bf(vv.x), hy = f2bf(vv.y), hz = f2bf(vv.z), hw = f2bf(vv.w);
    float lx = vv.x - bf2f(hx), ly = vv.y - bf2f(hy), lz = vv.z - bf2f(hz), lw = vv.w - bf2f(hw);
    uint2 hp = make_uint2((uint32_t)hx | ((uint32_t)hy << 16), (uint32_t)hz | ((uint32_t)hw << 16));
    uint2 lp = make_uint2((uint32_t)f2bf(lx) | ((uint32_t)f2bf(ly) << 16),
                          (uint32_t)f2bf(lz) | ((uint32_t)f2bf(lw) << 16));
    *((uint2*)(rowp + 64*hf + 8*x)) = hp;
    *((uint2*)(rowp + 128 + 64*hf + 8*x)) = lp;
  }
}

// ---------------- K1: row sumsq (f32+f64) + partial max (XBOX+ ext) ----------------
__global__ void k_norms2(const float* __restrict__ q, const float* __restrict__ kk,
                         float* __restrict__ qn2f, float* __restrict__ kn2f,
                         double* __restrict__ qn2d, double* __restrict__ kn2d,
                         double* __restrict__ qmaxp, double* __restrict__ kmaxp){
  __shared__ double red[256];
  int bx = blockIdx.x; int chunk = bx & 15, bh = bx >> 4;
  int tid = threadIdx.x;
  int b = bh >> 3, hh = bh & 7;
  int t = chunk*256 + tid;
  const float4* r1 = (const float4*)(q + (((size_t)(b*TT + t)*TH) + hh)*TE);
  double s = 0.0;
  #pragma unroll
  for(int x = 0; x < 16; x++){
    float4 vv = r1[x];
    s += (double)vv.x*vv.x + (double)vv.y*vv.y + (double)vv.z*vv.z + (double)vv.w*vv.w;
  }
  qn2d[bh*TT + t] = s; qn2f[bh*TT + t] = (float)s;
  const float4* r2 = (const float4*)(kk + (((size_t)(b*TT + t)*TH) + hh)*TE);
  double s2 = 0.0;
  #pragma unroll
  for(int x = 0; x < 16; x++){
    float4 vv = r2[x];
    s2 += (double)vv.x*vv.x + (double)vv.y*vv.y + (double)vv.z*vv.z + (double)vv.w*vv.w;
  }
  kn2d[bh*TT + t] = s2; kn2f[bh*TT + t] = (float)s2;
  red[tid] = s; __syncthreads();
  for(int o = 128; o > 0; o >>= 1){ if(tid < o) red[tid] = fmax(red[tid], red[tid+o]); __syncthreads(); }
  if(tid == 0) qmaxp[bh*16 + chunk] = red[0];
  __syncthreads();
  red[tid] = s2; __syncthreads();
  for(int o = 128; o > 0; o >>= 1){ if(tid < o) red[tid] = fmax(red[tid], red[tid+o]); __syncthreads(); }
  if(tid == 0) kmaxp[bh*16 + chunk] = red[0];
}

__global__ void k_mqk(const double* __restrict__ qmaxp, const double* __restrict__ kmaxp,
                      double* __restrict__ mqk2){
  int bh = blockIdx.x;
  if(threadIdx.x == 0){
    double mq = -1e300, mk = -1e300;
    for(int i = 0; i < 16; i++){ mq = fmax(mq, qmaxp[bh*16 + i]); mk = fmax(mk, kmaxp[bh*16 + i]); }
    mqk2[bh] = mq + mk;
  }
}

// ---------------- K2: E2LSH hashes (float64) ----------------
__global__ void k_hash(const float* __restrict__ q, const float* __restrict__ kk,
                       const float* __restrict__ alpha, const float* __restrict__ beta,
                       const double* __restrict__ qn2d, const double* __restrict__ kn2d,
                       const double* __restrict__ mqk2,
                       double* __restrict__ qh, double* __restrict__ kh){
  __shared__ double al[264];
  __shared__ double be[4];
  int tid = threadIdx.x;
  for(int i = tid; i < 264; i += 256) al[i] = (double)alpha[i];
  if(tid < 4) be[tid] = (double)beta[tid];
  __syncthreads();
  int gid = blockIdx.x*256 + tid;
  int side = gid >> 16; int r = gid & 65535;
  int bh = r >> 12, t = r & 4095;
  int b = bh >> 3, hh = bh & 7;
  const float* x = (side ? kk : q) + (((size_t)(b*TT + t)*TH) + hh)*TE;
  const float4* xr = (const float4*)x;
  double a0 = 0.0, a1 = 0.0, a2 = 0.0, a3 = 0.0;
  #pragma unroll
  for(int c = 0; c < 16; c++){
    float4 vv = xr[c];
    const double* a = al + c*16;
    a0 += (double)vv.x*a[0]  + (double)vv.y*a[4]  + (double)vv.z*a[8]  + (double)vv.w*a[12];
    a1 += (double)vv.x*a[1]  + (double)vv.y*a[5]  + (double)vv.z*a[9]  + (double)vv.w*a[13];
    a2 += (double)vv.x*a[2]  + (double)vv.y*a[6]  + (double)vv.z*a[10] + (double)vv.w*a[14];
    a3 += (double)vv.x*a[3]  + (double)vv.y*a[7]  + (double)vv.z*a[11] + (double)vv.w*a[15];
  }
  double n2  = (side ? kn2d : qn2d)[bh*TT + t];
  double ext = sqrt(fmax(mqk2[bh] - n2, 0.0));
  int ec = side ? 65 : 64;
  double* dst = side ? kh : qh;
  dst[((size_t)0*TBH + bh)*TT + t] = a0 + ext*al[ec*4 + 0] + be[0];
  dst[((size_t)1*TBH + bh)*TT + t] = a1 + ext*al[ec*4 + 1] + be[1];
  dst[((size_t)2*TBH + bh)*TT + t] = a2 + ext*al[ec*4 + 2] + be[2];
  dst[((size_t)3*TBH + bh)*TT + t] = a3 + ext*al[ec*4 + 3] + be[3];
}

// ---------------- K3: stable argsort via bitonic on doubles (1024 thr) ----------------
__global__ void k_sort(const double* __restrict__ qh, const double* __restrict__ kh,
                       int* __restrict__ qpos, int* __restrict__ kpos,
                       int* __restrict__ qrev, int* __restrict__ krev){
  __shared__ double v[4096];
  __shared__ int    ix[4096];
  int blk = blockIdx.x; int side = blk >> 6; int hb = blk & 63;
  const double* src = (side ? kh : qh) + (size_t)hb*TT;
  int tid = threadIdx.x;
  for(int i = tid; i < 4096; i += 1024){ v[i] = src[i]; ix[i] = i; }
  __syncthreads();
  for(int k = 2; k <= 4096; k <<= 1){
    for(int j = k >> 1; j > 0; j >>= 1){
      for(int i = tid; i < 4096; i += 1024){
        int l = i ^ j;
        if(l > i){
          double va = v[i], vb = v[l]; int ia = ix[i], ib = ix[l];
          bool gt  = (va > vb) || (va == vb && ia > ib);
          bool asc = ((i & k) == 0);
          if(gt == asc){ v[i] = vb; v[l] = va; ix[i] = ib; ix[l] = ia; }
        }
      }
      __syncthreads();
    }
  }
  int* pos = (side ? kpos : qpos) + (size_t)hb*TT;
  int* rev = (side ? krev : qrev) + (size_t)hb*TT;
  for(int i = tid; i < 4096; i += 1024){ int id = ix[i]; pos[i] = id; rev[id] = i; }
}

// ---------------- K4: dash GEMM via split-bf16 MFMA (both sides) ----------------
// 256 thr / 4 waves. Tile 128t x 256m, K=64. A = x rows, B = proj rows.
// side=0: qp = exp(dash - rowmax)*ratio + pls = rowmax (fused epilogue).
// side=1: kdash raw + block max -> klsp[bh*32+ch].
// Perturbs only the performer path (~1e-7 rel); pls/kls cancel algebraically.
__launch_bounds__(256, 1)
__global__ void k_dash(const float* __restrict__ q, const float* __restrict__ kk,
                       const float* __restrict__ proj,
                       const float* __restrict__ qn2f, const float* __restrict__ kn2f,
                       float* __restrict__ qp, float* __restrict__ kdash,
                       float* __restrict__ klsp, float* __restrict__ pls){
  __shared__ __align__(16) char xb[128*272];   // 34816: x rows bf16 hi|lo
  __shared__ __align__(16) char pb[256*272];   // 69632: proj rows bf16 hi|lo
  __shared__ float x_n[128];
  __shared__ float wred4[4];
  int tid = threadIdx.x;
  int w = tid >> 6, lane = tid & 63, l15 = lane & 15, quad = lane >> 4;
  int bx = blockIdx.x;
  int side = bx >> 9; int r0 = bx & 511; int bh = r0 >> 5; int ch = r0 & 31;
  int b = bh >> 3, hh = bh & 7, t0 = ch*128;
  const float* x  = side ? kk   : q;
  const float* n2 = side ? kn2f : qn2f;

  { int r = tid >> 1, hf = tid & 1;
    const float4* src = (const float4*)(x + (((size_t)(b*TT + t0 + r)*TH) + hh)*TE) + hf*8;
    stage64(xb + r*272, src, hf); }
  #pragma unroll
  for(int p = 0; p < 2; p++){
    int r = p*128 + (tid >> 1); int hf = tid & 1;
    const float4* src = (const float4*)(proj + (size_t)r*64) + hf*8;
    stage64(pb + r*272, src, hf);
  }
  if(tid < 128) x_n[tid] = n2[bh*TT + t0 + tid];
  __syncthreads();

  f32x4 acc[2][16];
  #pragma unroll
  for(int tt = 0; tt < 2; tt++)
    #pragma unroll
    for(int nt = 0; nt < 16; nt++) acc[tt][nt] = (f32x4){0.f,0.f,0.f,0.f};

  bf16x8 ahi[2][2], alo[2][2];
  #pragma unroll
  for(int tt = 0; tt < 2; tt++)
    #pragma unroll
    for(int ks = 0; ks < 2; ks++){
      const char* ap = xb + (32*w + 16*tt + l15)*272 + 64*ks + 16*quad;
      ahi[tt][ks] = *((const bf16x8*)ap);
      alo[tt][ks] = *((const bf16x8*)(ap + 128));
    }
  #pragma unroll 4
  for(int nt = 0; nt < 16; nt++){
    #pragma unroll
    for(int ks = 0; ks < 2; ks++){
      const char* bp = pb + (16*nt + l15)*272 + 64*ks + 16*quad;
      bf16x8 bhi = *((const bf16x8*)bp);
      bf16x8 blo = *((const bf16x8*)(bp + 128));
      #pragma unroll
      for(int tt = 0; tt < 2; tt++){
        acc[tt][nt] = __builtin_amdgcn_mfma_f32_16x16x32_bf16(ahi[tt][ks], bhi, acc[tt][nt], 0, 0, 0);
        acc[tt][nt] = __builtin_amdgcn_mfma_f32_16x16x32_bf16(ahi[tt][ks], blo, acc[tt][nt], 0, 0, 0);
        acc[tt][nt] = __builtin_amdgcn_mfma_f32_16x16x32_bf16(alo[tt][ks], bhi, acc[tt][nt], 0, 0, 0);
      }
    }
  }

  if(side == 0){
    #pragma unroll
    for(int tt = 0; tt < 2; tt++){
      #pragma unroll
      for(int e = 0; e < 4; e++){
        int t_r = 32*w + 16*tt + 4*quad + e;
        float diag = 0.5f*C_TEMP*x_n[t_r];
        float dv[16];
        float mx = -1e30f;
        #pragma unroll
        for(int nt = 0; nt < 16; nt++){
          dv[nt] = fmaf(C_DN, acc[tt][nt][e], -diag);
          mx = fmaxf(mx, dv[nt]);
        }
        #pragma unroll
        for(int s = 1; s < 16; s <<= 1) mx = fmaxf(mx, __shfl_xor(mx, s, 64));
        size_t rowbase = ((size_t)bh*TT + t0 + t_r)*256;
        #pragma unroll
        for(int nt = 0; nt < 16; nt++)
          qp[rowbase + l15 + 16*nt] = __expf(dv[nt] - mx)*C_RATIO;
        if(l15 == 0) pls[(size_t)bh*TT + t0 + t_r] = mx;
      }
    }
  } else {
    float mx = -1e30f;
    #pragma unroll
    for(int tt = 0; tt < 2; tt++){
      #pragma unroll
      for(int e = 0; e < 4; e++){
        int t_r = 32*w + 16*tt + 4*quad + e;
        float diag = 0.5f*C_TEMP*x_n[t_r];
        size_t rowbase = ((size_t)bh*TT + t0 + t_r)*256;
        #pragma unroll
        for(int nt = 0; nt < 16; nt++){
          float d = fmaf(C_DN, acc[tt][nt][e], -diag);
          kdash[rowbase + l15 + 16*nt] = d;
          mx = fmaxf(mx, d);
        }
      }
    }
    #pragma unroll
    for(int s = 32; s > 0; s >>= 1) mx = fmaxf(mx, __shfl_xor(mx, s, 64));
    if(lane == 0) wred4[w] = mx;
    __syncthreads();
    if(tid == 0)
      klsp[bh*32 + ch] = fmaxf(fmaxf(wred4[0], wred4[1]), fmaxf(wred4[2], wred4[3]));
  }
}

__global__ void k_klsred(const float* __restrict__ klsp, float* __restrict__ kls){
  int bh = blockIdx.x, tid = threadIdx.x;   // 64 threads
  float v = (tid < 32) ? klsp[bh*32 + tid] : -1e30f;
  #pragma unroll
  for(int o = 16; o > 0; o >>= 1) v = fmaxf(v, __shfl_xor(v, o, 64));
  if(tid == 0) kls[bh] = v;
}

// ---------------- K4c: kp = exp(dashK - kls)*ratio, in place (fp32) ----------------
__global__ void k_expk(float* __restrict__ kp, const float* __restrict__ kls){
  int tid = threadIdx.x; int blk = blockIdx.x;
  float4* p = (float4*)kp;
  size_t base = (size_t)blk*2048;
  float stab = kls[blk >> 7];
  #pragma unroll
  for(int i = 0; i < 8; i++){
    size_t ix = base + i*256 + tid;
    float4 vv = p[ix];
    vv.x = __expf(vv.x - stab)*C_RATIO; vv.y = __expf(vv.y - stab)*C_RATIO;
    vv.z = __expf(vv.z - stab)*C_RATIO; vv.w = __expf(vv.w - stab)*C_RATIO;
    p[ix] = vv;
  }
}

// ---------------- K5: kv partials over s-chunks, then reduce ----------------
// 8 consecutive m per thread -> 2 broadcast float4 loads per row (bit-identical sums).
__global__ void k_kv2(const float* __restrict__ kp, const float* __restrict__ v,
                      float* __restrict__ kvp, float* __restrict__ ksump){
  int bx = blockIdx.x; int sc = bx >> 7; int rem = bx & 127; int bh = rem >> 3; int mt = rem & 7;
  int tid = threadIdx.x; int g = tid >> 6, d = tid & 63;
  int b = bh >> 3, hh = bh & 7;
  int mbase = mt*32 + 8*g;
  float a[8], sa[8];
  #pragma unroll
  for(int j = 0; j < 8; j++){ a[j] = 0.f; sa[j] = 0.f; }
  const float* kpb = kp + (size_t)bh*TT*256 + mbase;
  const float* vb  = v + (size_t)b*TT*TH*TE + hh*TE + d;
  int s0 = sc*1024;
  #pragma unroll 4
  for(int s = s0; s < s0 + 1024; s++){
    float vv = vb[(size_t)s*512];
    const float4* kr = (const float4*)(kpb + (size_t)s*256);
    float4 k0 = kr[0], k1 = kr[1];
    float f[8] = {k0.x, k0.y, k0.z, k0.w, k1.x, k1.y, k1.z, k1.w};
    #pragma unroll
    for(int j = 0; j < 8; j++){ a[j] = fmaf(f[j], vv, a[j]); sa[j] += f[j]; }
  }
  #pragma unroll
  for(int j = 0; j < 8; j++){
    int m = mbase + j;
    kvp[(((size_t)sc*16 + bh)*256 + m)*64 + d] = a[j];
    if(d == 0) ksump[((size_t)sc*16 + bh)*256 + m] = sa[j];
  }
}

__global__ void k_kvred(const float* __restrict__ kvp, const float* __restrict__ ksump,
                        float* __restrict__ kv, float* __restrict__ ksum){
  int bx = blockIdx.x, tid = threadIdx.x;
  if(bx < 256){
    size_t i = (size_t)bx*1024 + tid*4;
    float4 s = make_float4(0.f,0.f,0.f,0.f);
    #pragma unroll
    for(int sc = 0; sc < 4; sc++){
      float4 p = *((const float4*)(kvp + (size_t)sc*262144 + i));
      s.x += p.x; s.y += p.y; s.z += p.z; s.w += p.w;
    }
    *((float4*)(kv + i)) = s;
  } else {
    for(int m = tid; m < 4096; m += 256){
      float s = 0.f;
      #pragma unroll
      for(int sc = 0; sc < 4; sc++) s += ksump[sc*4096 + m];
      ksum[m] = s;
    }
  }
}

// ---------------- K6: per-bucket attention, MFMA split-bf16 + reg prefetch ----------------
__launch_bounds__(256, 2)
__global__ void k_bucket(const float* __restrict__ q, const float* __restrict__ kk, const float* __restrict__ v,
                         const float* __restrict__ qp, const float* __restrict__ kp,
                         const int* __restrict__ qpos, const int* __restrict__ kpos,
                         const int* __restrict__ qrev, const int* __restrict__ krev,
                         const float* __restrict__ pls, const float* __restrict__ kls,
                         const float* __restrict__ qn2f, const float* __restrict__ kn2f,
                         float* __restrict__ o_t, float* __restrict__ lse_t, float* __restrict__ dsum_t){
  __shared__ __align__(16) char smem[73232];
  constexpr int OFS_B = 34816;
  int* qidxL   = (int*)(smem + 69632);
  int* kidxL   = (int*)(smem + 70144);
  int* qbpL    = (int*)(smem + 70656);
  int* kbpL    = (int*)(smem + 71168);
  float* lseL  = (float*)(smem + 71680);
  float* pfacL = (float*)(smem + 72192);
  float* kn2L  = (float*)(smem + 72704);
  float* kmaxP = (float*)(smem + 73216);

  int tid = threadIdx.x;
  int w = tid >> 6, lane = tid & 63, l15 = lane & 15, quad = lane >> 4;
  int bx = blockIdx.x; int n = bx & 31, bh = (bx >> 5) & 15, h = bx >> 9;
  int b = bh >> 3, hh = bh & 7;

  if(tid < 128){
    int tk = kpos[((size_t)h*TBH + bh)*TT + n*128 + tid];
    kidxL[tid] = tk;
    int pk = 0;
    #pragma unroll
    for(int h3 = 0; h3 < 4; h3++){ int rv = krev[((size_t)h3*TBH + bh)*TT + tk]; pk |= (rv >> 7) << (8*h3); }
    kbpL[tid] = pk;
    kn2L[tid] = kn2f[(size_t)bh*TT + tk];
    int tq = qpos[((size_t)h*TBH + bh)*TT + n*128 + tid];
    qidxL[tid] = tq;
    int pq = 0;
    #pragma unroll
    for(int h3 = 0; h3 < 4; h3++){ int rv = qrev[((size_t)h3*TBH + bh)*TT + tq]; pq |= (rv >> 7) << (8*h3); }
    qbpL[tid] = pq;
  }
  __syncthreads();
  if(tid < 64){
    float m = fmaxf(kn2L[tid], kn2L[tid + 64]);
    #pragma unroll
    for(int o = 32; o > 0; o >>= 1) m = fmaxf(m, __shfl_xor(m, o, 64));
    if(tid == 0) kmaxP[0] = m;
  }
  {  // stage Q into bufA, K into bufB (fp32 -> bf16 hi/lo)
    int r = tid >> 1, hf = tid & 1;
    const float4* qs = (const float4*)(q  + (((size_t)(b*TT + qidxL[r])*TH) + hh)*TE) + hf*8;
    const float4* ks = (const float4*)(kk + (((size_t)(b*TT + kidxL[r])*TH) + hh)*TE) + hf*8;
    stage64(smem + r*272, qs, hf);
    stage64(smem + OFS_B + r*272, ks, hf);
  }
  __syncthreads();
  if(tid < 128){  // per-row stabilizer (Cauchy-Schwarz UB) + pfac
    int tq = qidxL[tid];
    float plsv = pls[(size_t)bh*TT + tq] + kls[bh];
    float lse = fmaxf(plsv, C_TEMP * sqrtf(qn2f[(size_t)bh*TT + tq] * kmaxP[0]));
    lseL[tid] = lse;
    pfacL[tid] = __expf(plsv - lse);
  }

  // prefetch DP chunk 0 into registers (latency hides behind S MFMAs)
  float4 pq[8], pk2[8];
  { int r = tid >> 1, hf = tid & 1;
    const float4* qs = (const float4*)(qp + ((size_t)bh*TT + qidxL[r])*256) + hf*8;
    const float4* ks = (const float4*)(kp + ((size_t)bh*TT + kidxL[r])*256) + hf*8;
    #pragma unroll
    for(int i = 0; i < 8; i++){ pq[i] = qs[i]; pk2[i] = ks[i]; }
  }

  f32x4 acc_s[2][8], acc_p[2][8];
  #pragma unroll
  for(int mt = 0; mt < 2; mt++)
    #pragma unroll
    for(int nt = 0; nt < 8; nt++){
      acc_s[mt][nt] = (f32x4){0.f,0.f,0.f,0.f};
      acc_p[mt][nt] = (f32x4){0.f,0.f,0.f,0.f};
    }

  {  // S = Q K^T (K=64, split-3)
    bf16x8 ahi[2][2], alo[2][2];
    #pragma unroll
    for(int mt = 0; mt < 2; mt++)
      #pragma unroll
      for(int ks = 0; ks < 2; ks++){
        const char* ap = smem + (32*w + 16*mt + l15)*272 + 64*ks + 16*quad;
        ahi[mt][ks] = *((const bf16x8*)ap);
        alo[mt][ks] = *((const bf16x8*)(ap + 128));
      }
    #pragma unroll
    for(int nt = 0; nt < 8; nt++){
      #pragma unroll
      for(int ks = 0; ks < 2; ks++){
        const char* bp = smem + OFS_B + (16*nt + l15)*272 + 64*ks + 16*quad;
        bf16x8 bhi = *((const bf16x8*)bp);
        bf16x8 blo = *((const bf16x8*)(bp + 128));
        #pragma unroll
        for(int mt = 0; mt < 2; mt++){
          acc_s[mt][nt] = __builtin_amdgcn_mfma_f32_16x16x32_bf16(ahi[mt][ks], bhi, acc_s[mt][nt], 0, 0, 0);
          acc_s[mt][nt] = __builtin_amdgcn_mfma_f32_16x16x32_bf16(ahi[mt][ks], blo, acc_s[mt][nt], 0, 0, 0);
          acc_s[mt][nt] = __builtin_amdgcn_mfma_f32_16x16x32_bf16(alo[mt][ks], bhi, acc_s[mt][nt], 0, 0, 0);
        }
      }
    }
  }
  __syncthreads();

  // DP = QP KP^T (K=256 in 4 chunks, split-3), chunk c+1 / V prefetched in regs
  for(int c = 0; c < 4; c++){
    { int r = tid >> 1, hf = tid & 1;
      stage64r(smem + r*272, pq, hf);
      stage64r(smem + OFS_B + r*272, pk2, hf);
    }
    __syncthreads();
    if(c < 3){
      int r = tid >> 1, hf = tid & 1;
      const float4* qs = (const float4*)(qp + ((size_t)bh*TT + qidxL[r])*256 + (c+1)*64) + hf*8;
      const float4* ks = (const float4*)(kp + ((size_t)bh*TT + kidxL[r])*256 + (c+1)*64) + hf*8;
      #pragma unroll
      for(int i = 0; i < 8; i++){ pq[i] = qs[i]; pk2[i] = ks[i]; }
    } else {
      int j = tid >> 1, hc = tid & 1;
      const float4* vs = (const float4*)(v + (((size_t)(b*TT + kidxL[j])*TH) + hh)*TE) + hc*8;
      #pragma unroll
      for(int i = 0; i < 8; i++) pq[i] = vs[i];   // reuse pq for V
    }
    bf16x8 ahi[2][2], alo[2][2];
    #pragma unroll
    for(int mt = 0; mt < 2; mt++)
      #pragma unroll
      for(int ks = 0; ks < 2; ks++){
        const char* ap = smem + (32*w + 16*mt + l15)*272 + 64*ks + 16*quad;
        ahi[mt][ks] = *((const bf16x8*)ap);
        alo[mt][ks] = *((const bf16x8*)(ap + 128));
      }
    #pragma unroll
    for(int nt = 0; nt < 8; nt++){
      #pragma unroll
      for(int ks = 0; ks < 2; ks++){
        const char* bp = smem + OFS_B + (16*nt + l15)*272 + 64*ks + 16*quad;
        bf16x8 bhi = *((const bf16x8*)bp);
        bf16x8 blo = *((const bf16x8*)(bp + 128));
        #pragma unroll
        for(int mt = 0; mt < 2; mt++){
          acc_p[mt][nt] = __builtin_amdgcn_mfma_f32_16x16x32_bf16(ahi[mt][ks], bhi, acc_p[mt][nt], 0, 0, 0);
          acc_p[mt][nt] = __builtin_amdgcn_mfma_f32_16x16x32_bf16(ahi[mt][ks], blo, acc_p[mt][nt], 0, 0, 0);
          acc_p[mt][nt] = __builtin_amdgcn_mfma_f32_16x16x32_bf16(alo[mt][ks], bhi, acc_p[mt][nt], 0, 0, 0);
        }
      }
    }
    __syncthreads();
  }

  {  // stage V^T into bufB from prefetched regs (bf16 hi/lo, transposed)
    int j = tid >> 1, hc = tid & 1;
    #pragma unroll
    for(int x = 0; x < 8; x++){
      float4 vv = pq[x];
      int c0 = hc*32 + 4*x;
      float vals[4] = {vv.x, vv.y, vv.z, vv.w};
      #pragma unroll
      for(int i = 0; i < 4; i++){
        uint16_t hi = f2bf(vals[i]);
        float lo = vals[i] - bf2f(hi);
        *((uint16_t*)(smem + OFS_B + (c0 + i)*528 + 2*j)) = hi;
        *((uint16_t*)(smem + OFS_B + (c0 + i)*528 + 256 + 2*j)) = f2bf(lo);
      }
    }
  }
  int qbp_r[8]; float lse_r[8], pfac_r[8], dsump[8]; int kbp_c[8];
  #pragma unroll
  for(int i = 0; i < 8; i++){
    int r = 32*w + 16*(i >> 2) + 4*quad + (i & 3);
    qbp_r[i] = qbpL[r]; lse_r[i] = lseL[r]; pfac_r[i] = pfacL[r]; dsump[i] = 0.f;
  }
  #pragma unroll
  for(int nt = 0; nt < 8; nt++) kbp_c[nt] = kbpL[l15 + 16*nt];
  __syncthreads();

  // D (elementwise in C-layout regs) -> LDS bf16 hi/lo -> O += D V (two col-halves)
  f32x4 acc_o[2][4];
  #pragma unroll
  for(int mt = 0; mt < 2; mt++)
    #pragma unroll
    for(int nv = 0; nv < 4; nv++) acc_o[mt][nv] = (f32x4){0.f,0.f,0.f,0.f};

  #pragma unroll
  for(int hv = 0; hv < 2; hv++){
    #pragma unroll
    for(int nt = 0; nt < 4; nt++){
      int ntg = 4*hv + nt;
      #pragma unroll
      for(int mt = 0; mt < 2; mt++){
        f32x4 s4 = acc_s[mt][ntg], p4 = acc_p[mt][ntg];
        #pragma unroll
        for(int e = 0; e < 4; e++){
          int i = mt*4 + e;
          int du = dupc((uint32_t)(qbp_r[i] ^ kbp_c[ntg]));
          float ein  = __expf(fmaf(C_TEMP, s4[e], -lndup(du)) - lse_r[i]);
          float dots = fmaf(-p4[e]*rcpdup(du), pfac_r[i], ein);
          dsump[i] += dots;
          int row = 32*w + 16*mt + 4*quad + e;
          int colL = l15 + 16*nt;
          uint16_t hi = f2bf(dots);
          float lo = dots - bf2f(hi);
          *((uint16_t*)(smem + row*272 + 2*colL)) = hi;
          *((uint16_t*)(smem + row*272 + 128 + 2*colL)) = f2bf(lo);
        }
      }
    }
    bf16x8 dhi[2][2], dlo[2][2];
    #pragma unroll
    for(int mt = 0; mt < 2; mt++)
      #pragma unroll
      for(int ks = 0; ks < 2; ks++){
        const char* ap = smem + (32*w + 16*mt + l15)*272 + 64*ks + 16*quad;
        dhi[mt][ks] = *((const bf16x8*)ap);
        dlo[mt][ks] = *((const bf16x8*)(ap + 128));
      }
    #pragma unroll
    for(int nv = 0; nv < 4; nv++){
      #pragma unroll
      for(int ks = 0; ks < 2; ks++){
        const char* bp = smem + OFS_B + (16*nv + l15)*528 + 128*hv + 64*ks + 16*quad;
        bf16x8 vhi = *((const bf16x8*)bp);
        bf16x8 vlo = *((const bf16x8*)(bp + 256));
        #pragma unroll
        for(int mt = 0; mt < 2; mt++){
          acc_o[mt][nv] = __builtin_amdgcn_mfma_f32_16x16x32_bf16(dhi[mt][ks], vhi, acc_o[mt][nv], 0, 0, 0);
          acc_o[mt][nv] = __builtin_amdgcn_mfma_f32_16x16x32_bf16(dhi[mt][ks], vlo, acc_o[mt][nv], 0, 0, 0);
          acc_o[mt][nv] = __builtin_amdgcn_mfma_f32_16x16x32_bf16(dlo[mt][ks], vhi, acc_o[mt][nv], 0, 0, 0);
        }
      }
    }
  }

  // epilogue
  #pragma unroll
  for(int i = 0; i < 8; i++){
    float s = dsump[i];
    s += __shfl_xor(s, 1, 64); s += __shfl_xor(s, 2, 64);
    s += __shfl_xor(s, 4, 64); s += __shfl_xor(s, 8, 64);
    dsump[i] = s;
  }
  size_t obase = ((size_t)h*TBH + bh)*TT;
  if(l15 == 0){
    #pragma unroll
    for(int i = 0; i < 8; i++){
      int r = 32*w + 16*(i >> 2) + 4*quad + (i & 3);
      int tq = qidxL[r];
      lse_t [obase + tq] = lse_r[i];
      dsum_t[obase + tq] = dsump[i];
    }
  }
  #pragma unroll
  for(int mt = 0; mt < 2; mt++){
    #pragma unroll
    for(int e = 0; e < 4; e++){
      int r = 32*w + 16*mt + 4*quad + e;
      int tq = qidxL[r];
      float* orow = o_t + (obase + tq)*64;
      #pragma unroll
      for(int nv = 0; nv < 4; nv++) orow[l15 + 16*nv] = acc_o[mt][nv][e];
    }
  }
}

// ---------------- K7: fused qkv GEMM + hash-round combine ----------------
__launch_bounds__(512, 1)
__global__ void k_final2(const float* __restrict__ qp, const float* __restrict__ kv,
                         const float* __restrict__ ksum, const float* __restrict__ o_t,
                         const float* __restrict__ lse_t, const float* __restrict__ dsum_t,
                         const float* __restrict__ pls, const float* __restrict__ kls,
                         float* __restrict__ out){
  __shared__ __align__(16) float kv_l[256*68];
  __shared__ __align__(16) float qp_l[128*68];
  __shared__ float prL[128][4];
  __shared__ float pscL[128];
  __shared__ float nrmL[128];
  int tid = threadIdx.x;
  int bx = blockIdx.x; int bh = bx >> 5, ch = bx & 31;
  int b = bh >> 3, hh = bh & 7;
  int t0 = ch*128;
  {
    const float4* kv4 = (const float4*)(kv + (size_t)bh*16384);
    #pragma unroll
    for(int i = 0; i < 8; i++){
      int idx = i*512 + tid;
      int m = idx >> 4, d4 = idx & 15;
      *((float4*)(kv_l + m*68 + d4*4)) = kv4[idx];
    }
    if(tid < 256) kv_l[tid*68 + 64] = ksum[bh*256 + tid];
  }
  int c = tid & 15, tb = tid >> 4;
  float4 acc[4];
  #pragma unroll
  for(int tt = 0; tt < 4; tt++) acc[tt] = make_float4(0.f,0.f,0.f,0.f);
  float p1 = 0.f;
  for(int c4 = 0; c4 < 4; c4++){
    __syncthreads();
    #pragma unroll
    for(int it = 0; it < 4; it++){
      int r = it*32 + tb;
      *((float4*)(qp_l + r*68 + c*4)) =
        *((const float4*)(qp + ((size_t)bh*TT + t0 + r)*256 + c4*64 + c*4));
    }
    __syncthreads();
    #pragma unroll 4
    for(int m4 = 0; m4 < 16; m4++){
      float4 qv[4];
      #pragma unroll
      for(int tt = 0; tt < 4; tt++)
        qv[tt] = *((const float4*)(qp_l + (tb + 32*tt)*68 + m4*4));
      #pragma unroll
      for(int mm = 0; mm < 4; mm++){
        int m = c4*64 + m4*4 + mm;
        float4 kvv = *((const float4*)(kv_l + m*68 + c*4));
        #pragma unroll
        for(int tt = 0; tt < 4; tt++){
          float qs = (mm == 0) ? qv[tt].x : (mm == 1) ? qv[tt].y : (mm == 2) ? qv[tt].z : qv[tt].w;
          acc[tt].x = fmaf(qs, kvv.x, acc[tt].x);
          acc[tt].y = fmaf(qs, kvv.y, acc[tt].y);
          acc[tt].z = fmaf(qs, kvv.z, acc[tt].z);
          acc[tt].w = fmaf(qs, kvv.w, acc[tt].w);
        }
      }
    }
    if(tid < 128){
      #pragma unroll 8
      for(int m = 0; m < 64; m++)
        p1 = fmaf(qp_l[tid*68 + m], kv_l[(c4*64 + m)*68 + 64], p1);
    }
  }
  __syncthreads();
  if(tid < 128){
    int t = t0 + tid;
    float l0 = lse_t[((size_t)0*TBH + bh)*TT + t], l1 = lse_t[((size_t)1*TBH + bh)*TT + t];
    float l2 = lse_t[((size_t)2*TBH + bh)*TT + t], l3 = lse_t[((size_t)3*TBH + bh)*TT + t];
    float M = fmaxf(fmaxf(l0, l1), fmaxf(l2, l3));
    float e0 = __expf(l0 - M), e1 = __expf(l1 - M), e2 = __expf(l2 - M), e3 = __expf(l3 - M);
    float rs = 1.f / (e0 + e1 + e2 + e3);
    float pr0 = e0*rs, pr1 = e1*rs, pr2 = e2*rs, pr3 = e3*rs;
    float psc = __expf(pls[bh*TT + t] + kls[bh] - M)*rs;
    float nrm = 0.f;
    nrm = fmaf(dsum_t[((size_t)0*TBH + bh)*TT + t], pr0, nrm);
    nrm = fmaf(dsum_t[((size_t)1*TBH + bh)*TT + t], pr1, nrm);
    nrm = fmaf(dsum_t[((size_t)2*TBH + bh)*TT + t], pr2, nrm);
    nrm = fmaf(dsum_t[((size_t)3*TBH + bh)*TT + t], pr3, nrm);
    nrm = fmaf(p1, psc, nrm);
    prL[tid][0] = pr0; prL[tid][1] = pr1; prL[tid][2] = pr2; prL[tid][3] = pr3;
    pscL[tid] = psc;
    nrmL[tid] = fmaxf(nrm, 1e-6f);
  }
  __syncthreads();
  #pragma unroll
  for(int tt = 0; tt < 4; tt++){
    int r = tb + 32*tt; int t = t0 + r;
    float4 o0 = *((const float4*)(o_t + (((size_t)0*TBH + bh)*TT + t)*64 + c*4));
    float4 o1 = *((const float4*)(o_t + (((size_t)1*TBH + bh)*TT + t)*64 + c*4));
    float4 o2 = *((const float4*)(o_t + (((size_t)2*TBH + bh)*TT + t)*64 + c*4));
    float4 o3 = *((const float4*)(o_t + (((size_t)3*TBH + bh)*TT + t)*64 + c*4));
    float pr0 = prL[r][0], pr1 = prL[r][1], pr2 = prL[r][2], pr3 = prL[r][3];
    float psc = pscL[r], nrm = nrmL[r];
    float4 outl;
    outl.x = fmaf(o3.x, pr3, fmaf(o2.x, pr2, fmaf(o1.x, pr1, o0.x*pr0)));
    outl.y = fmaf(o3.y, pr3, fmaf(o2.y, pr2, fmaf(o1.y, pr1, o0.y*pr0)));
    outl.z = fmaf(o3.z, pr3, fmaf(o2.z, pr2, fmaf(o1.z, pr1, o0.z*pr0)));
    outl.w = fmaf(o3.w, pr3, fmaf(o2.w, pr2, fmaf(o1.w, pr1, o0.w*pr0)));
    float4 res;
    res.x = (outl.x + acc[tt].x*psc) / nrm;
    res.y = (outl.y + acc[tt].y*psc) / nrm;
    res.z = (outl.z + acc[tt].z*psc) / nrm;
    res.w = (outl.w + acc[tt].w*psc) / nrm;
    *((float4*)(out + ((size_t)(b*TT + t)*TH + hh)*64 + c*4)) = res;
  }
}

// sentinel: signals ws_size-too-small distinctly from a numeric bug
__global__ void k_sentinel(float* __restrict__ out, int n){
  int i = blockIdx.x*256 + threadIdx.x;
  if(i < n) out[i] = 12345.0f;
}

extern "C" void kernel_launch(void* const* d_in, const int* in_sizes, int n_in,
                              void* d_out, int out_size, void* d_ws, size_t ws_size,
                              hipStream_t stream){
  const float* q     = (const float*)d_in[0];
  const float* k     = (const float*)d_in[1];
  const float* v     = (const float*)d_in[2];
  const float* proj  = (const float*)d_in[3];
  const float* alpha = (const float*)d_in[4];
  const float* beta  = (const float*)d_in[5];
  float* out = (float*)d_out;
  char* ws = (char*)d_ws;

  if(ws_size < WS_NEED){
    k_sentinel<<<dim3((out_size + 255)/256), dim3(256), 0, stream>>>(out, out_size);
    return;
  }

  float*  qn2f  = (float*) (ws + OFF_QN2F);
  float*  kn2f  = (float*) (ws + OFF_KN2F);
  double* qn2d  = (double*)(ws + OFF_QN2D);
  double* kn2d  = (double*)(ws + OFF_KN2D);
  double* mqk2  = (double*)(ws + OFF_MQK2);
  double* qmaxp = (double*)(ws + OFF_QMAXP);
  double* kmaxp = (double*)(ws + OFF_KMAXP);
  double* qh    = (double*)(ws + OFF_QH);
  double* kh    = (double*)(ws + OFF_KH);
  int*   qpos   = (int*)  (ws + OFF_QPOS);
  int*   kpos   = (int*)  (ws + OFF_KPOS);
  int*   qrev   = (int*)  (ws + OFF_QREV);
  int*   krev   = (int*)  (ws + OFF_KREV);
  float* klsp   = (float*)(ws + OFF_KLSP);
  float* kls    = (float*)(ws + OFF_KLS);
  float* qp     = (float*)(ws + OFF_QP);
  float* kp     = (float*)(ws + OFF_KP);
  float* pls    = (float*)(ws + OFF_PLS);
  float* ksum   = (float*)(ws + OFF_KSUM);
  float* kvv    = (float*)(ws + OFF_KV);
  float* o_t    = (float*)(ws + OFF_OT);
  float* lse_t  = (float*)(ws + OFF_LSET);
  float* dsum_t = (float*)(ws + OFF_DSUM);
  float* kvp    = (float*)(ws + OFF_KVP);
  float* ksump  = (float*)(ws + OFF_KSP);

  k_norms2<<<dim3(256),   dim3(256),  0, stream>>>(q, k, qn2f, kn2f, qn2d, kn2d, qmaxp, kmaxp);
  k_mqk   <<<dim3(16),    dim3(64),   0, stream>>>(qmaxp, kmaxp, mqk2);
  k_hash  <<<dim3(512),   dim3(256),  0, stream>>>(q, k, alpha, beta, qn2d, kn2d, mqk2, qh, kh);
  k_sort  <<<dim3(128),   dim3(1024), 0, stream>>>(qh, kh, qpos, kpos, qrev, krev);
  k_dash  <<<dim3(1024),  dim3(256),  0, stream>>>(q, k, proj, qn2f, kn2f, qp, kp, klsp, pls);
  k_klsred<<<dim3(16),    dim3(64),   0, stream>>>(klsp, kls);
  k_expk  <<<dim3(2048),  dim3(256),  0, stream>>>(kp, kls);
  k_kv2   <<<dim3(512),   dim3(256),  0, stream>>>(kp, v, kvp, ksump);
  k_kvred <<<dim3(257),   dim3(256),  0, stream>>>(kvp, ksump, kvv, ksum);
  k_bucket<<<dim3(2048),  dim3(256),  0, stream>>>(q, k, v, qp, kp, qpos, kpos, qrev, krev, pls, kls, qn2f, kn2f, o_t, lse_t, dsum_t);
  k_final2<<<dim3(512),   dim3(512),  0, stream>>>(qp, kvv, ksum, o_t, lse_t, dsum_t, pls, kls, out);
}